// Round 8
// baseline (323.680 us; speedup 1.0000x reference)
//
#include <hip/hip_runtime.h>

// ---------------------------------------------------------------------------
// TransformerBlock: x:[2,2048,1024] fp32
//   qkv = x @ w_qkv;  attention (scale 1/sqrt(1024));  x = x + LN(attn_out)
//   ff  = relu(x@w1+b1)@w2+b2;  out = x + LN(ff)
// R15: faithful m201 8-phase GEMM port. BM=BN=256, BK=64, 8 waves (2Mx4N),
//     LDS 128KB As/Bs[2dbuf][2half][128][64]. Iter i processes K-tiles 2i
//     (dbuf0, phases 1-4) and 2i+1 (dbuf1, phases 5-8). Per phase:
//     {A-quad frag ds_read (4xb128; +8 B-frag reads at ph1/ph5) | stage one
//      16KB unit (2 gld_lds) | barrier | lgkmcnt(0)+schedbar | setprio(1)
//      16 MFMA | setprio(0) | [vmcnt(6) at ph4/ph8] | barrier}.
//     B-frags hoisted to regs once per K-tile; A read in 32-row quadrants.
//     Stage map: ph1=A[d1].j1(t2i+1) ph2/3=B[d0](t2i+2) ph4=A[d0].j0
//     ph5=A[d0].j1 ph6/7=B[d1](t2i+3) ph8=A[d1].j0; region ledger verified
//     (WAR: target's last reader >=1 barrier before issue; RAW: vmcnt(6)
//     retires every unit >=3 phases before first read). Chunk-XOR swizzle
//     c^=(row&7) on both DMA source and frag reads (involution).
//     attn = R8 frozen (62us best); LN wave-per-row, preps = R14 frozen.
// ---------------------------------------------------------------------------

typedef unsigned short u16;
typedef unsigned int u32;
typedef __bf16 bf16x8 __attribute__((ext_vector_type(8)));
typedef float f32x4 __attribute__((ext_vector_type(4)));
typedef float f32x16 __attribute__((ext_vector_type(16)));
typedef u32 u32x4 __attribute__((ext_vector_type(4)));
typedef u16 u16x4 __attribute__((ext_vector_type(4)));

__device__ __forceinline__ u16 f2b(float f) {
  u32 u = __builtin_bit_cast(u32, f);
  u += 0x7fffu + ((u >> 16) & 1u);       // RNE
  return (u16)(u >> 16);
}
__device__ __forceinline__ float b2f(u16 u) {
  return __builtin_bit_cast(float, (u32)u << 16);
}

// pack 2 fp32 -> 1 dword of 2 bf16 (RNE), lo in low half
__device__ __forceinline__ u32 cvtpk(float lo, float hi) {
  u32 r;
  asm("v_cvt_pk_bf16_f32 %0, %1, %2" : "=v"(r) : "v"(lo), "v"(hi));
  return r;
}

// async global->LDS DMA, 16B per lane. LDS dest = wave-uniform base + lane*16.
__device__ __forceinline__ void gld_lds16(const u16* g, u16* l) {
  __builtin_amdgcn_global_load_lds(
      (const __attribute__((address_space(1))) u32*)g,
      (__attribute__((address_space(3))) u32*)l, 16, 0, 0);
}

// ---------------------------------------------------------------------------
// 32x32 fp32->bf16 transpose tile helper (whole block must call).
__device__ __forceinline__ void transpose32(
    const float* __restrict__ in, u16* __restrict__ out, int R, int C,
    int bx, int by, float (*tile)[33], int tid) {
  const int cb = bx * 32, rb = by * 32;
  const int c = tid & 31;
  const int r0 = tid >> 5;
#pragma unroll
  for (int rr = 0; rr < 32; rr += 8)
    tile[r0 + rr][c] = in[(size_t)(rb + r0 + rr) * C + cb + c];
  __syncthreads();
#pragma unroll
  for (int rr = 0; rr < 32; rr += 8)
    out[(size_t)(cb + r0 + rr) * R + rb + c] = f2b(tile[c][r0 + rr]);
}

// prep1: blocks [0,4096): x fp32->bf16 convert. blocks [4096,7168): wqkv^T.
__global__ __launch_bounds__(256) void prep1_kernel(
    const float* __restrict__ x, u16* __restrict__ xb,
    const float* __restrict__ w_qkv, u16* __restrict__ wqkvT) {
  __shared__ float tile[32][33];
  const int bid = blockIdx.x;
  const int tid = threadIdx.x;
  if (bid < 4096) {
    const int idx = bid * 256 + tid;
    float4 v = ((const float4*)x)[idx];
    u16x4 o = { f2b(v.x), f2b(v.y), f2b(v.z), f2b(v.w) };
    ((u16x4*)xb)[idx] = o;
  } else {
    const int t = bid - 4096;
    transpose32(w_qkv, wqkvT, 1024, 3072, t % 96, t / 96, tile, tid);
  }
}

// prep2: blocks [0,4096): w1^T (1024x4096). blocks [4096,8192): w2^T (4096x1024).
__global__ __launch_bounds__(256) void prep2_kernel(
    const float* __restrict__ w1, u16* __restrict__ w1T,
    const float* __restrict__ w2, u16* __restrict__ w2T) {
  __shared__ float tile[32][33];
  const int bid = blockIdx.x;
  const int tid = threadIdx.x;
  if (bid < 4096) {
    transpose32(w1, w1T, 1024, 4096, bid % 128, bid / 128, tile, tid);
  } else {
    const int t = bid - 4096;
    transpose32(w2, w2T, 4096, 1024, t % 32, t / 32, tile, tid);
  }
}

// V part of qkv [s][d] -> vt[bh][d][s]  (bf16 copy-transpose, 64x64 tiles)
__global__ __launch_bounds__(256) void transpose_v_kernel(
    const u16* __restrict__ qkv, u16* __restrict__ vt) {
  __shared__ u16 t[64][70];
  const int bh = blockIdx.x, st = blockIdx.y;
  const int b = bh >> 4, nh = bh & 15;
  const int s0 = st * 64;
  const int r = threadIdx.x >> 3, c = (threadIdx.x & 7) << 3;
  const u16* src = qkv + (size_t)(b * 2048 + s0) * 3072 + 2048 + nh * 64;
#pragma unroll
  for (int rr = 0; rr < 64; rr += 32)
    *(u32x4*)&t[r + rr][c] = *(const u32x4*)(src + (size_t)(r + rr) * 3072 + c);
  __syncthreads();
  u16* dst = vt + ((size_t)bh * 64) * 2048 + s0;
#pragma unroll
  for (int rr = 0; rr < 64; rr += 32) {
    const int d = r + rr;
    u16 tmp[8];
#pragma unroll
    for (int j = 0; j < 8; ++j) tmp[j] = t[c + j][d];
    *(u32x4*)(dst + (size_t)d * 2048 + c) = *(u32x4*)tmp;
  }
}

// ---------------------------------------------------------------------------
// C[M,N] = A[M,K](bf16) @ Bt[N,K](bf16)^T, fp32 accum, bf16 out.
// m201-style 8-phase schedule; see R15 header. K-per-block = 1024 (16 tiles)
// hardcoded; split-K via gridDim.y (z*1024 K-offset).
// Requires M%256==0, N%256==0, gridDim.x%8==0.

// stage one 8KB issue: 64 rows (rb..rb+63), wave w covers rows rb+w*8..+7
#define STG_A(D, H, RB, T) \
  gld_lds16(AgS + (size_t)((H) * 128 + (RB)) * K + (size_t)(T) * 64, &As[D][H][(RB) + w8][0]);
#define STG_B(D, H, RB, T) \
  gld_lds16(BgS + (size_t)((H) * 128 + (RB)) * K + (size_t)(T) * 64, &Bs[D][H][(RB) + w8][0]);

// B fragments for the wave's 64 cols, both k-steps (8 x ds_read_b128)
#define LDB(D)                                                                \
  _Pragma("unroll") for (int nr = 0; nr < 4; ++nr)                            \
    _Pragma("unroll") for (int s = 0; s < 2; ++s)                             \
      bfr[nr][s] = *(const bf16x8*)&Bs[D][bh_][bn_ + nr * 16 + l16]           \
                                      [((s * 4 + quad) ^ (l16 & 7)) * 8];

// one phase: A-quad frag reads | stage | barrier | lgkm | 16 MFMA | [vm] | barrier
#define PH(D, Q, STAGE, VM)                                                   \
  {                                                                           \
    bf16x8 aqf[2][2];                                                         \
    _Pragma("unroll") for (int mi = 0; mi < 2; ++mi)                          \
      _Pragma("unroll") for (int s = 0; s < 2; ++s)                           \
        aqf[mi][s] = *(const bf16x8*)&As[D][wm][(2 * (Q) + mi) * 16 + l16]    \
                                        [((s * 4 + quad) ^ (l16 & 7)) * 8];   \
    STAGE                                                                     \
    __builtin_amdgcn_s_barrier();                                             \
    asm volatile("s_waitcnt lgkmcnt(0)" ::: "memory");                        \
    __builtin_amdgcn_sched_barrier(0);                                        \
    __builtin_amdgcn_s_setprio(1);                                            \
    _Pragma("unroll") for (int mi = 0; mi < 2; ++mi)                          \
      _Pragma("unroll") for (int nr = 0; nr < 4; ++nr)                        \
        _Pragma("unroll") for (int s = 0; s < 2; ++s)                         \
          acc[2 * (Q) + mi][nr] = __builtin_amdgcn_mfma_f32_16x16x32_bf16(    \
              aqf[mi][s], bfr[nr][s], acc[2 * (Q) + mi][nr], 0, 0, 0);        \
    __builtin_amdgcn_s_setprio(0);                                            \
    VM                                                                        \
    __builtin_amdgcn_s_barrier();                                             \
  }

#define VM6 asm volatile("s_waitcnt vmcnt(6)" ::: "memory");
#define VM0 asm volatile("s_waitcnt vmcnt(0)" ::: "memory");

__global__ __launch_bounds__(512) void gemm256_kernel(
    const u16* __restrict__ A, const u16* __restrict__ Bt,
    const float* __restrict__ bias, u16* __restrict__ Cb,
    int M, int N, int K, int relu,
    u16* __restrict__ Cb1, u16* __restrict__ Cb2, u16* __restrict__ Cb3) {
  // XCD-chunked bijective swizzle (gridDim.x % 8 == 0)
  const int nN = N >> 8;
  const int lin = (blockIdx.x & 7) * ((int)gridDim.x >> 3) + (blockIdx.x >> 3);
  const int m0 = (lin / nN) << 8;
  const int n0 = (lin % nN) << 8;
  const int z = blockIdx.y;
  if (z == 1) Cb = Cb1; else if (z == 2) Cb = Cb2; else if (z == 3) Cb = Cb3;

  const int tid = threadIdx.x;
  const int w = tid >> 6, lane = tid & 63;
  const int quad = lane >> 4, l16 = lane & 15;
  const int wm = w >> 2, wn = w & 3;
  const int bh_ = wn >> 1, bn_ = (wn & 1) * 64;   // B half / within-half base

  __shared__ u16 As[2][2][128][64];   // [dbuf][half][row][k] 64KB
  __shared__ u16 Bs[2][2][128][64];   // 64KB

  f32x4 acc[8][4];
#pragma unroll
  for (int i = 0; i < 8; ++i)
#pragma unroll
    for (int j = 0; j < 4; ++j) acc[i][j] = {0.f, 0.f, 0.f, 0.f};

  // staging: issue = 64 rows x 64 K (8KB); wave w rows w*8+(l>>3); chunk
  // pre-swizzled (l&7)^(l>>3) so LDS[row][c] holds global chunk c^(row&7).
  const int sr8 = lane >> 3;
  const int sc8 = ((lane & 7) ^ sr8) << 3;          // u16 units
  const int w8 = w * 8;
  const u16* AgS = A + (size_t)(m0 + w8 + sr8) * K + (size_t)z * 1024 + sc8;
  const u16* BgS = Bt + (size_t)(n0 + w8 + sr8) * K + (size_t)z * 1024 + sc8;

  bf16x8 bfr[4][2];

  // prologue: tile 0 fully (8 issues) + tile 1 minus A.j1 (6 issues)
  STG_B(0, 0, 0, 0)  STG_B(0, 0, 64, 0)  STG_B(0, 1, 0, 0)  STG_B(0, 1, 64, 0)
  STG_A(0, 0, 0, 0)  STG_A(0, 1, 0, 0)   STG_A(0, 0, 64, 0) STG_A(0, 1, 64, 0)
  STG_B(1, 0, 0, 1)  STG_B(1, 0, 64, 1)  STG_B(1, 1, 0, 1)  STG_B(1, 1, 64, 1)
  STG_A(1, 0, 0, 1)  STG_A(1, 1, 0, 1)
  asm volatile("s_waitcnt vmcnt(0)" ::: "memory");
  __builtin_amdgcn_s_barrier();

  for (int i = 0; i < 7; ++i) {
    const int t1 = 2 * i + 1, t2 = 2 * i + 2, t3 = 2 * i + 3;
    LDB(0)
    PH(0, 0, STG_A(1, 0, 64, t1) STG_A(1, 1, 64, t1), )
    PH(0, 1, STG_B(0, 0, 0, t2) STG_B(0, 0, 64, t2), )
    PH(0, 2, STG_B(0, 1, 0, t2) STG_B(0, 1, 64, t2), )
    PH(0, 3, STG_A(0, 0, 0, t2) STG_A(0, 1, 0, t2), VM6)
    LDB(1)
    PH(1, 0, STG_A(0, 0, 64, t2) STG_A(0, 1, 64, t2), )
    PH(1, 1, STG_B(1, 0, 0, t3) STG_B(1, 0, 64, t3), )
    PH(1, 2, STG_B(1, 1, 0, t3) STG_B(1, 1, 64, t3), )
    PH(1, 3, STG_A(1, 0, 0, t3) STG_A(1, 1, 0, t3), VM6)
  }
  // final iteration (tiles 14, 15): only tile15.A.j1 left to stage
  LDB(0)
  PH(0, 0, STG_A(1, 0, 64, 15) STG_A(1, 1, 64, 15), )
  PH(0, 1, , )
  PH(0, 2, , )
  PH(0, 3, , VM0)
  LDB(1)
  PH(1, 0, , )
  PH(1, 1, , )
  PH(1, 2, , )
  PH(1, 3, , )

  // epilogue: wave writes 128 rows x 64 cols
#pragma unroll
  for (int mr = 0; mr < 8; ++mr) {
    const int row = m0 + wm * 128 + mr * 16 + quad * 4;
#pragma unroll
    for (int nr = 0; nr < 4; ++nr) {
      const int col = n0 + wn * 64 + nr * 16 + l16;
      const float bv = bias ? bias[col] : 0.f;
#pragma unroll
      for (int r = 0; r < 4; ++r) {
        float v = acc[mr][nr][r] + bv;
        if (relu) v = fmaxf(v, 0.f);
        Cb[(size_t)(row + r) * N + col] = f2b(v);
      }
    }
  }
}

// ---------------------------------------------------------------------------
// Flash attention (R8, best measured), fixed-max softmax, key-split kz in {0,1}.
// Block = (bh, 128 q-rows, 1024-key range); 4 waves x 32 q-rows.
// 32x32x16 MFMA, swapped QK^T (S^T = K.Q^T): lane owns query = lane&31.
// P fragments built in-register via cvt_pk_bf16 + permlane32_swap.
// Writes UNNORMALIZED O partial (fp32) + l partial; LN1 combines.
__global__ __launch_bounds__(256, 4) void attn_kernel(
    const u16* __restrict__ qkv, const u16* __restrict__ vt,
    float* __restrict__ Op0, float* __restrict__ Op1,
    float* __restrict__ lpart) {
  const int bh = blockIdx.x;          // b*16 + nh
  const int qt = blockIdx.y;          // 0..15
  const int kz = blockIdx.z;          // 0..1
  const int b = bh >> 4, nh = bh & 15;
  const int tid = threadIdx.x;
  const int w = tid >> 6, lane = tid & 63;
  const int l32 = lane & 31, hi = lane >> 5;
  const float c2 = 0.04508422f;       // log2(e)/sqrt(1024)

  __shared__ u16 KS[64][64];          // K tile [key][d], chunk-swizzled
  __shared__ u16 VS[64][64];          // V^T tile [d][key], chunk-swizzled

  const size_t rs = 3072;
  const u16* qbase = qkv + (size_t)b * 2048 * rs + nh * 64;
  const u16* kbase = qbase + 1024;
  const u16* vbase = vt + (size_t)bh * 64 * 2048;
  const int q0 = qt * 128;
  const int k0beg = kz * 1024;

  // Q fragments to registers, pre-scaled by c2.
  bf16x8 aq[4];
  {
    const u16* qrow = qbase + (size_t)(q0 + w * 32 + l32) * rs + hi * 8;
#pragma unroll
    for (int ds = 0; ds < 4; ++ds) {
      u32x4 v = *(const u32x4*)(qrow + ds * 16);
      u16 ti[8], to[8];
      *(u32x4*)ti = v;
#pragma unroll
      for (int j = 0; j < 8; ++j) to[j] = f2b(b2f(ti[j]) * c2);
      u32x4 pk = *(u32x4*)to;
      aq[ds] = __builtin_bit_cast(bf16x8, pk);
    }
  }

  f32x16 Oacc[2];
#pragma unroll
  for (int dn = 0; dn < 2; ++dn)
#pragma unroll
    for (int i = 0; i < 16; ++i) Oacc[dn][i] = 0.f;
  float ls[4] = {0.f, 0.f, 0.f, 0.f};

  // staging map: lane l -> row (l>>3), 16B chunk (l&7) ^ (row&7)  (XOR swz)
  const int srow = lane >> 3;                       // 0..7
  const int scol = ((lane & 7) ^ srow) << 3;        // u16 units, swizzled

#pragma unroll 1
  for (int t = 0; t < 16; ++t) {
    const int k0 = k0beg + t * 64;
    __syncthreads();                  // all waves done with prev tile
    gld_lds16(kbase + (size_t)(k0 + w * 16 + srow) * rs + scol,       &KS[w * 16][0]);
    gld_lds16(kbase + (size_t)(k0 + w * 16 + 8 + srow) * rs + scol,   &KS[w * 16 + 8][0]);
    gld_lds16(vbase + (size_t)(w * 16 + srow) * 2048 + k0 + scol,     &VS[w * 16][0]);
    gld_lds16(vbase + (size_t)(w * 16 + 8 + srow) * 2048 + k0 + scol, &VS[w * 16 + 8][0]);
    __syncthreads();                  // barrier drains vmcnt -> DMA visible

    // S^T = K . Q^T : lane holds S^T[key = 32*jt + crow(r,hi)][query = l32]
    f32x16 S[2];
#pragma unroll
    for (int jt = 0; jt < 2; ++jt)
#pragma unroll
      for (int i = 0; i < 16; ++i) S[jt][i] = 0.f;
#pragma unroll
    for (int jt = 0; jt < 2; ++jt) {
      const int krow = jt * 32 + l32;
#pragma unroll
      for (int ds = 0; ds < 4; ++ds) {
        bf16x8 kv = *(const bf16x8*)&KS[krow][((2 * ds + hi) ^ (krow & 7)) << 3];
        S[jt] = __builtin_amdgcn_mfma_f32_32x32x16_bf16(kv, aq[ds], S[jt], 0, 0, 0);
      }
    }

    // p = exp2(S^T); build PV A-fragments in-register.
    bf16x8 pa[4];
#pragma unroll
    for (int jt = 0; jt < 2; ++jt) {
      float p[16];
#pragma unroll
      for (int r = 0; r < 16; ++r) {
        p[r] = exp2f(S[jt][r]);
        ls[r & 3] += p[r];
      }
#pragma unroll
      for (int bq = 0; bq < 2; ++bq) {
        u32 x0 = cvtpk(p[8 * bq + 0], p[8 * bq + 1]);
        u32 y0 = cvtpk(p[8 * bq + 4], p[8 * bq + 5]);
        u32 x1 = cvtpk(p[8 * bq + 2], p[8 * bq + 3]);
        u32 y1 = cvtpk(p[8 * bq + 6], p[8 * bq + 7]);
        asm("v_permlane32_swap_b32 %0, %1" : "+v"(x0), "+v"(y0));
        asm("v_permlane32_swap_b32 %0, %1" : "+v"(x1), "+v"(y1));
        u32x4 dw = {x0, x1, y0, y1};  // keys {0,1},{2,3},{4,5},{6,7} (+8hi)
        pa[2 * jt + bq] = __builtin_bit_cast(bf16x8, dw);
      }
    }

    // O += P V : lane holds O[query = crow(r,hi)][d = dn*32 + l32]
#pragma unroll
    for (int dn = 0; dn < 2; ++dn) {
      const int vrow = dn * 32 + l32;
#pragma unroll
      for (int ks = 0; ks < 4; ++ks) {
        bf16x8 vv = *(const bf16x8*)&VS[vrow][((2 * ks + hi) ^ (vrow & 7)) << 3];
        Oacc[dn] = __builtin_amdgcn_mfma_f32_32x32x16_bf16(pa[ks], vv, Oacc[dn], 0, 0, 0);
      }
    }
  }

  // l: per-lane partial covers this hi's keys; add partner half (lane^32)
  float lsum = (ls[0] + ls[1]) + (ls[2] + ls[3]);
  const float ltot = lsum + __shfl_xor(lsum, 32);

  float* opart = kz ? Op1 : Op0;
  float* obase = opart + (size_t)b * 2048 * 1024 + (size_t)nh * 64;
  float* lbase = lpart + (size_t)kz * 4096 * 16 + (size_t)b * 2048 * 16 + nh;
#pragma unroll
  for (int r = 0; r < 16; ++r) {
    const int qrow = q0 + w * 32 + (r & 3) + 8 * (r >> 2) + 4 * hi;
#pragma unroll
    for (int dn = 0; dn < 2; ++dn)
      obase[(size_t)qrow * 1024 + dn * 32 + l32] = Oacc[dn][r];
  }
  if (lane < 32) lbase[(size_t)(q0 + w * 32 + l32) * 16] = ltot;
}

// ---------------------------------------------------------------------------
// x1 = xres + LN((O0+O1)/(l0+l1))*g + b ; writes fp32 + bf16.
// Wave-per-row: grid 1024 x 4 waves; lane holds 4 stride-64 float4s; pure
// shfl_xor reduce (no LDS/barrier).
__global__ __launch_bounds__(256) void ln_attn_kernel(
    const float* __restrict__ O0, const float* __restrict__ O1,
    const float* __restrict__ l0, const float* __restrict__ l1,
    const float* __restrict__ xres, const float* __restrict__ g,
    const float* __restrict__ bb, float* __restrict__ outf,
    u16* __restrict__ outb) {
  const int w = threadIdx.x >> 6, lane = threadIdx.x & 63;
  const int row = blockIdx.x * 4 + w;
  const float4* o0r = (const float4*)(O0 + (size_t)row * 1024);
  const float4* o1r = (const float4*)(O1 + (size_t)row * 1024);
  const float* lp0 = l0 + row * 16;
  const float* lp1 = l1 + row * 16;

  float4 v[4];
  float s = 0.f, s2 = 0.f;
#pragma unroll
  for (int j = 0; j < 4; ++j) {
    const int f = j * 64 + lane;            // float4 index in row (0..255)
    const int head = f >> 4;                // all 4 elems same head
    const float inv = 1.f / (lp0[head] + lp1[head]);
    float4 a0 = o0r[f];
    float4 a1 = o1r[f];
    v[j].x = (a0.x + a1.x) * inv;
    v[j].y = (a0.y + a1.y) * inv;
    v[j].z = (a0.z + a1.z) * inv;
    v[j].w = (a0.w + a1.w) * inv;
    s  += v[j].x + v[j].y + v[j].z + v[j].w;
    s2 += v[j].x * v[j].x + v[j].y * v[j].y + v[j].z * v[j].z + v[j].w * v[j].w;
  }
#pragma unroll
  for (int off = 32; off > 0; off >>= 1) {
    s += __shfl_xor(s, off);
    s2 += __shfl_xor(s2, off);
  }
  const float mu = s * (1.f / 1024.f);
  const float var = s2 * (1.f / 1024.f) - mu * mu;
  const float rstd = rsqrtf(var + 1e-5f);

  const float4* xr4 = (const float4*)(xres + (size_t)row * 1024);
  float4* of4 = (float4*)(outf + (size_t)row * 1024);
  u16x4* ob4 = (u16x4*)(outb + (size_t)row * 1024);
#pragma unroll
  for (int j = 0; j < 4; ++j) {
    const int f = j * 64 + lane;
    float4 xr = xr4[f];
    float4 gv = ((const float4*)g)[f];
    float4 bv = ((const float4*)bb)[f];
    float4 o;
    o.x = xr.x + (v[j].x - mu) * rstd * gv.x + bv.x;
    o.y = xr.y + (v[j].y - mu) * rstd * gv.y + bv.y;
    o.z = xr.z + (v[j].z - mu) * rstd * gv.z + bv.z;
    o.w = xr.w + (v[j].w - mu) * rstd * gv.w + bv.w;
    of4[f] = o;
    u16x4 ob = { f2b(o.x), f2b(o.y), f2b(o.z), f2b(o.w) };
    ob4[f] = ob;
  }
}

// ---------------------------------------------------------------------------
// out = xres + LN(p0+p1+p2+p3 + bias)*g + b  (FFN2 split-K combine), fp32 out.
// Wave-per-row (same structure as ln_attn).
__global__ __launch_bounds__(256) void ln_ffn_kernel(
    const u16* __restrict__ p0, const u16* __restrict__ p1,
    const u16* __restrict__ p2, const u16* __restrict__ p3,
    const float* __restrict__ bias, const float* __restrict__ xres,
    const float* __restrict__ g, const float* __restrict__ bb,
    float* __restrict__ outf) {
  const int w = threadIdx.x >> 6, lane = threadIdx.x & 63;
  const int row = blockIdx.x * 4 + w;
  const u16x4* p0r = (const u16x4*)(p0 + (size_t)row * 1024);
  const u16x4* p1r = (const u16x4*)(p1 + (size_t)row * 1024);
  const u16x4* p2r = (const u16x4*)(p2 + (size_t)row * 1024);
  const u16x4* p3r = (const u16x4*)(p3 + (size_t)row * 1024);

  float4 v[4];
  float s = 0.f, s2 = 0.f;
#pragma unroll
  for (int j = 0; j < 4; ++j) {
    const int f = j * 64 + lane;
    u16x4 a0 = p0r[f];
    u16x4 a1 = p1r[f];
    u16x4 a2 = p2r[f];
    u16x4 a3 = p3r[f];
    float4 bv4 = ((const float4*)bias)[f];
    v[j].x = (b2f(a0[0]) + b2f(a1[0])) + (b2f(a2[0]) + b2f(a3[0])) + bv4.x;
    v[j].y = (b2f(a0[1]) + b2f(a1[1])) + (b2f(a2[1]) + b2f(a3[1])) + bv4.y;
    v[j].z = (b2f(a0[2]) + b2f(a1[2])) + (b2f(a2[2]) + b2f(a3[2])) + bv4.z;
    v[j].w = (b2f(a0[3]) + b2f(a1[3])) + (b2f(a2[3]) + b2f(a3[3])) + bv4.w;
    s  += v[j].x + v[j].y + v[j].z + v[j].w;
    s2 += v[j].x * v[j].x + v[j].y * v[j].y + v[j].z * v[j].z + v[j].w * v[j].w;
  }
#pragma unroll
  for (int off = 32; off > 0; off >>= 1) {
    s += __shfl_xor(s, off);
    s2 += __shfl_xor(s2, off);
  }
  const float mu = s * (1.f / 1024.f);
  const float var = s2 * (1.f / 1024.f) - mu * mu;
  const float rstd = rsqrtf(var + 1e-5f);

  const float4* xr4 = (const float4*)(xres + (size_t)row * 1024);
  float4* of4 = (float4*)(outf + (size_t)row * 1024);
#pragma unroll
  for (int j = 0; j < 4; ++j) {
    const int f = j * 64 + lane;
    float4 xr = xr4[f];
    float4 gv = ((const float4*)g)[f];
    float4 bv = ((const float4*)bb)[f];
    float4 o;
    o.x = xr.x + (v[j].x - mu) * rstd * gv.x + bv.x;
    o.y = xr.y + (v[j].y - mu) * rstd * gv.y + bv.y;
    o.z = xr.z + (v[j].z - mu) * rstd * gv.z + bv.z;
    o.w = xr.w + (v[j].w - mu) * rstd * gv.w + bv.w;
    of4[f] = o;
  }
}

// ---------------------------------------------------------------------------
extern "C" void kernel_launch(void* const* d_in, const int* in_sizes, int n_in,
                              void* d_out, int out_size, void* d_ws, size_t ws_size,
                              hipStream_t stream) {
  const float* x     = (const float*)d_in[0];
  const float* w_qkv = (const float*)d_in[1];
  const float* ln1_g = (const float*)d_in[2];
  const float* ln1_b = (const float*)d_in[3];
  const float* w1    = (const float*)d_in[4];
  const float* b1    = (const float*)d_in[5];
  const float* w2    = (const float*)d_in[6];
  const float* b2    = (const float*)d_in[7];
  const float* ln2_g = (const float*)d_in[8];
  const float* ln2_b = (const float*)d_in[9];
  float* out = (float*)d_out;
  char* ws = (char*)d_ws;

  // workspace (lifetime-aliased; max end = 98,566,144 B):
  u16*   xb    = (u16*)(ws + 0);              // [0,8.4M)     dead after qkv gemm
  u16*   wqkvT = (u16*)(ws + 8388608);        // [8.4,14.7M)  dead after qkv gemm
  u16*   qkvb  = (u16*)(ws + 31457280);       // [31.5,56.6M) dead after attn
  u16*   vT    = (u16*)(ws + 56623104);       // [56.6,73.4M) dead after attn
  float* Op0   = (float*)(ws + 0);            // [0,16.8M)    attn partial 0 (over dead xb/wqkvT)
  float* Op1   = (float*)(ws + 73400320);     // [73.4,90.2M) attn partial 1
  float* lp    = (float*)(ws + 90177536);     // [90.2,90.7M) l partials (2x256KB)
  float* x1    = (float*)(ws + 31457280);     // [31.5,48.2M) over dead qkvb (after attn)
  u16*   x1b   = (u16*)(ws + 48234496);       // [48.2,56.6M) over dead qkvb; dead after FFN1
  u16*   w1T   = (u16*)(ws + 14680064);       // [14.7,23.1M) written after LN1 (over dead Op0)
  u16*   w2T   = (u16*)(ws + 23068672);       // [23.1,31.5M) written after LN1
  u16*   h1    = (u16*)(ws + 56623104);       // [56.6,90.2M) over dead vT+Op1
  u16*   fp0   = (u16*)(ws + 0);              // FFN2 partials (over dead Op0/lp/x1b)
  u16*   fp1   = (u16*)(ws + 8388608);
  u16*   fp2   = (u16*)(ws + 48234496);
  u16*   fp3   = (u16*)(ws + 90177536);

  // prep1: x->bf16 convert + wqkv transpose (fused, 4096+3072 blocks)
  prep1_kernel<<<7168, 256, 0, stream>>>(x, xb, w_qkv, wqkvT);

  // qkv: M=4096 N=3072 K=1024 -> 192 blocks
  gemm256_kernel<<<dim3(192, 1), 512, 0, stream>>>(
      xb, wqkvT, nullptr, qkvb, 4096, 3072, 1024, 0,
      nullptr, nullptr, nullptr);
  transpose_v_kernel<<<dim3(32, 32), 256, 0, stream>>>(qkvb, vT);
  attn_kernel<<<dim3(32, 16, 2), 256, 0, stream>>>(qkvb, vT, Op0, Op1, lp);

  ln_attn_kernel<<<1024, 256, 0, stream>>>(
      Op0, Op1, lp, lp + 4096 * 16, x, ln1_g, ln1_b, x1, x1b);

  // prep2: w1 + w2 transposes (fused, 4096+4096 blocks)
  prep2_kernel<<<8192, 256, 0, stream>>>(w1, w1T, w2, w2T);

  // FFN1: M=4096 N=4096 K=1024 -> 256 blocks
  gemm256_kernel<<<dim3(256, 1), 512, 0, stream>>>(
      x1b, w1T, b1, h1, 4096, 4096, 1024, 1,
      nullptr, nullptr, nullptr);
  // FFN2: M=4096 N=1024 K=4096, split-K=4 -> 64x4 blocks
  gemm256_kernel<<<dim3(64, 4), 512, 0, stream>>>(
      h1, w2T, nullptr, fp0, 4096, 1024, 4096, 0,
      fp1, fp2, fp3);

  ln_ffn_kernel<<<1024, 256, 0, stream>>>(
      fp0, fp1, fp2, fp3, b2, x1, ln2_g, ln2_b, out);
}

// Round 9
// 308.415 us; speedup vs baseline: 1.0495x; 1.0495x over previous
//
#include <hip/hip_runtime.h>

// ---------------------------------------------------------------------------
// TransformerBlock: x:[2,2048,1024] fp32
//   qkv = x @ w_qkv;  attention (scale 1/sqrt(1024));  x = x + LN(attn_out)
//   ff  = relu(x@w1+b1)@w2+b2;  out = x + LN(ff)
// R16: qkv GEMM full-CU fill. Old tiling 256x256 -> 16x12 = 192 blocks = 25%
//     of CUs idle for the whole dispatch (the only misfit grid; FFN1/FFN2
//     are exactly 256). New qkv kernel: BM=256 x BN=192 -> 16x16 = 256
//     blocks. R12 structure (BK=32, 3 LDS buffers, 1 barrier/tile, counted
//     vmcnt). B staging: rows 0-127 all waves + rows 128-191 by waves 0-3
//     only -> per-wave-class vmcnt ledger (w<4: 4, w>=4: 3); each wave
//     retires its OWN t+1 issues, barrier joins. acc[8][3] (96 VGPR).
//     R15's 8-phase port was null vs R12 (3 schedules within +-3us ->
//     schedule-insensitive at K=1024 / 1 block/CU); GEMM = R12 kept.
//     attn = R8 frozen (62us best); LN wave-per-row + preps = R14 frozen.
// ---------------------------------------------------------------------------

typedef unsigned short u16;
typedef unsigned int u32;
typedef __bf16 bf16x8 __attribute__((ext_vector_type(8)));
typedef float f32x4 __attribute__((ext_vector_type(4)));
typedef float f32x16 __attribute__((ext_vector_type(16)));
typedef u32 u32x4 __attribute__((ext_vector_type(4)));
typedef u16 u16x4 __attribute__((ext_vector_type(4)));

__device__ __forceinline__ u16 f2b(float f) {
  u32 u = __builtin_bit_cast(u32, f);
  u += 0x7fffu + ((u >> 16) & 1u);       // RNE
  return (u16)(u >> 16);
}
__device__ __forceinline__ float b2f(u16 u) {
  return __builtin_bit_cast(float, (u32)u << 16);
}

// pack 2 fp32 -> 1 dword of 2 bf16 (RNE), lo in low half
__device__ __forceinline__ u32 cvtpk(float lo, float hi) {
  u32 r;
  asm("v_cvt_pk_bf16_f32 %0, %1, %2" : "=v"(r) : "v"(lo), "v"(hi));
  return r;
}

// async global->LDS DMA, 16B per lane. LDS dest = wave-uniform base + lane*16.
__device__ __forceinline__ void gld_lds16(const u16* g, u16* l) {
  __builtin_amdgcn_global_load_lds(
      (const __attribute__((address_space(1))) u32*)g,
      (__attribute__((address_space(3))) u32*)l, 16, 0, 0);
}

// ---------------------------------------------------------------------------
// 32x32 fp32->bf16 transpose tile helper (whole block must call).
__device__ __forceinline__ void transpose32(
    const float* __restrict__ in, u16* __restrict__ out, int R, int C,
    int bx, int by, float (*tile)[33], int tid) {
  const int cb = bx * 32, rb = by * 32;
  const int c = tid & 31;
  const int r0 = tid >> 5;
#pragma unroll
  for (int rr = 0; rr < 32; rr += 8)
    tile[r0 + rr][c] = in[(size_t)(rb + r0 + rr) * C + cb + c];
  __syncthreads();
#pragma unroll
  for (int rr = 0; rr < 32; rr += 8)
    out[(size_t)(cb + r0 + rr) * R + rb + c] = f2b(tile[c][r0 + rr]);
}

// prep1: blocks [0,4096): x fp32->bf16 convert. blocks [4096,7168): wqkv^T.
__global__ __launch_bounds__(256) void prep1_kernel(
    const float* __restrict__ x, u16* __restrict__ xb,
    const float* __restrict__ w_qkv, u16* __restrict__ wqkvT) {
  __shared__ float tile[32][33];
  const int bid = blockIdx.x;
  const int tid = threadIdx.x;
  if (bid < 4096) {
    const int idx = bid * 256 + tid;
    float4 v = ((const float4*)x)[idx];
    u16x4 o = { f2b(v.x), f2b(v.y), f2b(v.z), f2b(v.w) };
    ((u16x4*)xb)[idx] = o;
  } else {
    const int t = bid - 4096;
    transpose32(w_qkv, wqkvT, 1024, 3072, t % 96, t / 96, tile, tid);
  }
}

// prep2: blocks [0,4096): w1^T (1024x4096). blocks [4096,8192): w2^T (4096x1024).
__global__ __launch_bounds__(256) void prep2_kernel(
    const float* __restrict__ w1, u16* __restrict__ w1T,
    const float* __restrict__ w2, u16* __restrict__ w2T) {
  __shared__ float tile[32][33];
  const int bid = blockIdx.x;
  const int tid = threadIdx.x;
  if (bid < 4096) {
    transpose32(w1, w1T, 1024, 4096, bid % 128, bid / 128, tile, tid);
  } else {
    const int t = bid - 4096;
    transpose32(w2, w2T, 4096, 1024, t % 32, t / 32, tile, tid);
  }
}

// V part of qkv [s][d] -> vt[bh][d][s]  (bf16 copy-transpose, 64x64 tiles)
__global__ __launch_bounds__(256) void transpose_v_kernel(
    const u16* __restrict__ qkv, u16* __restrict__ vt) {
  __shared__ u16 t[64][70];
  const int bh = blockIdx.x, st = blockIdx.y;
  const int b = bh >> 4, nh = bh & 15;
  const int s0 = st * 64;
  const int r = threadIdx.x >> 3, c = (threadIdx.x & 7) << 3;
  const u16* src = qkv + (size_t)(b * 2048 + s0) * 3072 + 2048 + nh * 64;
#pragma unroll
  for (int rr = 0; rr < 64; rr += 32)
    *(u32x4*)&t[r + rr][c] = *(const u32x4*)(src + (size_t)(r + rr) * 3072 + c);
  __syncthreads();
  u16* dst = vt + ((size_t)bh * 64) * 2048 + s0;
#pragma unroll
  for (int rr = 0; rr < 64; rr += 32) {
    const int d = r + rr;
    u16 tmp[8];
#pragma unroll
    for (int j = 0; j < 8; ++j) tmp[j] = t[c + j][d];
    *(u32x4*)(dst + (size_t)d * 2048 + c) = *(u32x4*)tmp;
  }
}

// ---------------------------------------------------------------------------
// C[M,N] = A[M,K](bf16) @ Bt[N,K](bf16)^T, fp32 accum, bf16 out. (R12)
// 256x256 tile, BK=32, 8 waves, 3 LDS buffers, one barrier/tile, vmcnt(4).
#define GT(BUF, SBUF, T2, VM)                                                 \
  {                                                                           \
    const u16(*Ab)[32] = As[BUF];                                             \
    const u16(*Bb)[32] = Bs[BUF];                                             \
    bf16x8 af[4], bfr[4];                                                     \
    _Pragma("unroll") for (int nr = 0; nr < 4; ++nr)                          \
        bfr[nr] = *(const bf16x8*)&Bb[wn * 64 + nr * 16 + l16][cRd];          \
    _Pragma("unroll") for (int mr = 0; mr < 4; ++mr)                          \
        af[mr] = *(const bf16x8*)&Ab[wm * 128 + mr * 16 + l16][cRd];          \
    if ((T2) >= 0) {                                                          \
      gld_lds16(Ag + (size_t)(T2) * 32,         &As[SBUF][w * 16][0]);        \
      gld_lds16(Ag + rstep + (size_t)(T2) * 32, &As[SBUF][128 + w * 16][0]);  \
    }                                                                         \
    asm volatile("s_waitcnt lgkmcnt(0)" ::: "memory");                        \
    __builtin_amdgcn_sched_barrier(0);                                        \
    __builtin_amdgcn_s_setprio(1);                                            \
    _Pragma("unroll") for (int mr = 0; mr < 4; ++mr)                          \
        _Pragma("unroll") for (int nr = 0; nr < 4; ++nr)                      \
            acc[mr][nr] = __builtin_amdgcn_mfma_f32_16x16x32_bf16(            \
                af[mr], bfr[nr], acc[mr][nr], 0, 0, 0);                       \
    __builtin_amdgcn_s_setprio(0);                                            \
    _Pragma("unroll") for (int mr = 0; mr < 4; ++mr)                          \
        af[mr] = *(const bf16x8*)&Ab[wm * 128 + 64 + mr * 16 + l16][cRd];     \
    if ((T2) >= 0) {                                                          \
      gld_lds16(Bg + (size_t)(T2) * 32,         &Bs[SBUF][w * 16][0]);        \
      gld_lds16(Bg + rstep + (size_t)(T2) * 32, &Bs[SBUF][128 + w * 16][0]);  \
    }                                                                         \
    asm volatile("s_waitcnt lgkmcnt(0)" ::: "memory");                        \
    __builtin_amdgcn_sched_barrier(0);                                        \
    __builtin_amdgcn_s_setprio(1);                                            \
    _Pragma("unroll") for (int mr = 0; mr < 4; ++mr)                          \
        _Pragma("unroll") for (int nr = 0; nr < 4; ++nr)                      \
            acc[4 + mr][nr] = __builtin_amdgcn_mfma_f32_16x16x32_bf16(        \
                af[mr], bfr[nr], acc[4 + mr][nr], 0, 0, 0);                   \
    __builtin_amdgcn_s_setprio(0);                                            \
    if ((VM) == 4) asm volatile("s_waitcnt vmcnt(4)" ::: "memory");           \
    else if ((VM) == 0) asm volatile("s_waitcnt vmcnt(0)" ::: "memory");      \
    if ((VM) >= 0) __builtin_amdgcn_s_barrier();                              \
  }

__global__ __launch_bounds__(512) void gemm256_kernel(
    const u16* __restrict__ A, const u16* __restrict__ Bt,
    const float* __restrict__ bias, u16* __restrict__ Cb,
    int M, int N, int K, int relu,
    u16* __restrict__ Cb1, u16* __restrict__ Cb2, u16* __restrict__ Cb3) {
  const int nN = N >> 8;
  const int lin = (blockIdx.x & 7) * ((int)gridDim.x >> 3) + (blockIdx.x >> 3);
  const int m0 = (lin / nN) << 8;
  const int n0 = (lin % nN) << 8;
  const int z = blockIdx.y;
  if (z == 1) Cb = Cb1; else if (z == 2) Cb = Cb2; else if (z == 3) Cb = Cb3;

  const int tid = threadIdx.x;
  const int w = tid >> 6, lane = tid & 63;
  const int quad = lane >> 4, l16 = lane & 15;
  const int wm = w >> 2, wn = w & 3;

  __shared__ u16 As[3][256][32];
  __shared__ u16 Bs[3][256][32];

  f32x4 acc[8][4];
#pragma unroll
  for (int i = 0; i < 8; ++i)
#pragma unroll
    for (int j = 0; j < 4; ++j) acc[i][j] = {0.f, 0.f, 0.f, 0.f};

  const int srow = lane >> 2;                               // 0..15
  const int scol = (((lane & 3) ^ (srow & 3)) << 3);        // u16 units
  const u16* Ag = A + (size_t)(m0 + w * 16 + srow) * K + (size_t)z * 1024 + scol;
  const u16* Bg = Bt + (size_t)(n0 + w * 16 + srow) * K + (size_t)z * 1024 + scol;
  const size_t rstep = (size_t)128 * K;

  const int cRd = ((quad ^ (l16 & 3)) << 3);                // u16 units

  gld_lds16(Ag,              &As[0][w * 16][0]);
  gld_lds16(Ag + rstep,      &As[0][128 + w * 16][0]);
  gld_lds16(Bg,              &Bs[0][w * 16][0]);
  gld_lds16(Bg + rstep,      &Bs[0][128 + w * 16][0]);
  gld_lds16(Ag + 32,         &As[1][w * 16][0]);
  gld_lds16(Ag + rstep + 32, &As[1][128 + w * 16][0]);
  gld_lds16(Bg + 32,         &Bs[1][w * 16][0]);
  gld_lds16(Bg + rstep + 32, &Bs[1][128 + w * 16][0]);
  asm volatile("s_waitcnt vmcnt(4)" ::: "memory");
  __builtin_amdgcn_s_barrier();

  for (int tt = 0; tt < 10; ++tt) {
    const int t = tt * 3;
    GT(0, 2, t + 2, 4)
    GT(1, 0, t + 3, 4)
    GT(2, 1, t + 4, 4)
  }
  GT(0, 0, -1, 0)    // tile 30
  GT(1, 0, -1, -1)   // tile 31

#pragma unroll
  for (int mr = 0; mr < 8; ++mr) {
    const int row = m0 + wm * 128 + mr * 16 + quad * 4;
#pragma unroll
    for (int nr = 0; nr < 4; ++nr) {
      const int col = n0 + wn * 64 + nr * 16 + l16;
      const float bv = bias ? bias[col] : 0.f;
#pragma unroll
      for (int r = 0; r < 4; ++r) {
        float v = acc[mr][nr][r] + bv;
        if (relu) v = fmaxf(v, 0.f);
        Cb[(size_t)(row + r) * N + col] = f2b(v);
      }
    }
  }
}

// ---------------------------------------------------------------------------
// qkv GEMM: C[4096,3072] = A[4096,1024] @ Bt[3072,1024]^T, bf16 out.
// BM=256 x BN=192 -> grid 16x16 = 256 blocks (full CU fill; old 256x256 was
// 192 blocks = 25% CUs idle). R12 structure: BK=32, 3 LDS buffers, one
// barrier/tile, counted vmcnt. B staged as rows 0-127 (all waves) + rows
// 128-191 (waves 0-3 only) -> wave-class vmcnt: w<4 keeps 4/tile in flight,
// w>=4 keeps 3/tile. Per wave: 128 rows x 48 cols, acc[8][3].
#define QVM4                                                                  \
  if (w < 4) { asm volatile("s_waitcnt vmcnt(4)" ::: "memory"); }             \
  else       { asm volatile("s_waitcnt vmcnt(3)" ::: "memory"); }
#define QGT(BUF, SBUF, T2, VM)                                                \
  {                                                                           \
    const u16(*Ab)[32] = As[BUF];                                             \
    const u16(*Bb)[32] = Bs[BUF];                                             \
    bf16x8 af[4], bfr[3];                                                     \
    _Pragma("unroll") for (int nr = 0; nr < 3; ++nr)                          \
        bfr[nr] = *(const bf16x8*)&Bb[wn * 48 + nr * 16 + l16][cRd];          \
    _Pragma("unroll") for (int mr = 0; mr < 4; ++mr)                          \
        af[mr] = *(const bf16x8*)&Ab[wm * 128 + mr * 16 + l16][cRd];          \
    if ((T2) >= 0) {                                                          \
      gld_lds16(Ag + (size_t)(T2) * 32,         &As[SBUF][w * 16][0]);        \
      gld_lds16(Ag + rstep + (size_t)(T2) * 32, &As[SBUF][128 + w * 16][0]);  \
    }                                                                         \
    asm volatile("s_waitcnt lgkmcnt(0)" ::: "memory");                        \
    __builtin_amdgcn_sched_barrier(0);                                        \
    __builtin_amdgcn_s_setprio(1);                                            \
    _Pragma("unroll") for (int mr = 0; mr < 4; ++mr)                          \
        _Pragma("unroll") for (int nr = 0; nr < 3; ++nr)                      \
            acc[mr][nr] = __builtin_amdgcn_mfma_f32_16x16x32_bf16(            \
                af[mr], bfr[nr], acc[mr][nr], 0, 0, 0);                       \
    __builtin_amdgcn_s_setprio(0);                                            \
    _Pragma("unroll") for (int mr = 0; mr < 4; ++mr)                          \
        af[mr] = *(const bf16x8*)&Ab[wm * 128 + 64 + mr * 16 + l16][cRd];     \
    if ((T2) >= 0) {                                                          \
      gld_lds16(Bg + (size_t)(T2) * 32,         &Bs[SBUF][w * 16][0]);        \
      if (w < 4)                                                              \
        gld_lds16(Bg2 + (size_t)(T2) * 32,      &Bs[SBUF][128 + w * 16][0]);  \
    }                                                                         \
    asm volatile("s_waitcnt lgkmcnt(0)" ::: "memory");                        \
    __builtin_amdgcn_sched_barrier(0);                                        \
    __builtin_amdgcn_s_setprio(1);                                            \
    _Pragma("unroll") for (int mr = 0; mr < 4; ++mr)                          \
        _Pragma("unroll") for (int nr = 0; nr < 3; ++nr)                      \
            acc[4 + mr][nr] = __builtin_amdgcn_mfma_f32_16x16x32_bf16(        \
                af[mr], bfr[nr], acc[4 + mr][nr], 0, 0, 0);                   \
    __builtin_amdgcn_s_setprio(0);                                            \
    if ((VM) == 4) { QVM4 }                                                   \
    else if ((VM) == 0) asm volatile("s_waitcnt vmcnt(0)" ::: "memory");      \
    if ((VM) >= 0) __builtin_amdgcn_s_barrier();                              \
  }

__global__ __launch_bounds__(512) void gemm_qkv_kernel(
    const u16* __restrict__ A, const u16* __restrict__ Bt,
    u16* __restrict__ Cb) {
  const int K = 1024, N = 3072;
  // XCD-chunked bijective swizzle over 256 blocks (16 M-panels x 16 N-panels)
  const int lin = (blockIdx.x & 7) * 32 + (blockIdx.x >> 3);
  const int m0 = (lin >> 4) << 8;          // 256-row panel
  const int n0 = (lin & 15) * 192;         // 192-col panel

  const int tid = threadIdx.x;
  const int w = tid >> 6, lane = tid & 63;
  const int quad = lane >> 4, l16 = lane & 15;
  const int wm = w >> 2, wn = w & 3;

  __shared__ u16 As[3][256][32];           // 48KB
  __shared__ u16 Bs[3][192][32];           // 36KB

  f32x4 acc[8][3];
#pragma unroll
  for (int i = 0; i < 8; ++i)
#pragma unroll
    for (int j = 0; j < 3; ++j) acc[i][j] = {0.f, 0.f, 0.f, 0.f};

  const int srow = lane >> 2;                               // 0..15
  const int scol = (((lane & 3) ^ (srow & 3)) << 3);        // u16 units
  const u16* Ag = A + (size_t)(m0 + w * 16 + srow) * K + scol;
  const u16* Bg = Bt + (size_t)(n0 + w * 16 + srow) * K + scol;
  const u16* Bg2 = Bt + (size_t)(n0 + 128 + w * 16 + srow) * K + scol; // w<4
  const size_t rstep = (size_t)128 * K;

  const int cRd = ((quad ^ (l16 & 3)) << 3);                // u16 units

  // prologue: stage k-tiles 0 and 1
  gld_lds16(Ag,              &As[0][w * 16][0]);
  gld_lds16(Ag + rstep,      &As[0][128 + w * 16][0]);
  gld_lds16(Bg,              &Bs[0][w * 16][0]);
  if (w < 4) gld_lds16(Bg2,  &Bs[0][128 + w * 16][0]);
  gld_lds16(Ag + 32,         &As[1][w * 16][0]);
  gld_lds16(Ag + rstep + 32, &As[1][128 + w * 16][0]);
  gld_lds16(Bg + 32,         &Bs[1][w * 16][0]);
  if (w < 4) gld_lds16(Bg2 + 32, &Bs[1][128 + w * 16][0]);
  QVM4
  __builtin_amdgcn_s_barrier();

  for (int tt = 0; tt < 10; ++tt) {
    const int t = tt * 3;
    QGT(0, 2, t + 2, 4)
    QGT(1, 0, t + 3, 4)
    QGT(2, 1, t + 4, 4)
  }
  QGT(0, 0, -1, 0)    // tile 30: drain
  QGT(1, 0, -1, -1)   // tile 31

  // epilogue: wave writes 128 rows x 48 cols
#pragma unroll
  for (int mr = 0; mr < 8; ++mr) {
    const int row = m0 + wm * 128 + mr * 16 + quad * 4;
#pragma unroll
    for (int nr = 0; nr < 3; ++nr) {
      const int col = n0 + wn * 48 + nr * 16 + l16;
#pragma unroll
      for (int r = 0; r < 4; ++r)
        Cb[(size_t)(row + r) * N + col] = f2b(acc[mr][nr][r]);
    }
  }
}

// ---------------------------------------------------------------------------
// Flash attention (R8, best measured), fixed-max softmax, key-split kz in {0,1}.
// Block = (bh, 128 q-rows, 1024-key range); 4 waves x 32 q-rows.
// 32x32x16 MFMA, swapped QK^T (S^T = K.Q^T): lane owns query = lane&31.
// P fragments built in-register via cvt_pk_bf16 + permlane32_swap.
// Writes UNNORMALIZED O partial (fp32) + l partial; LN1 combines.
__global__ __launch_bounds__(256, 4) void attn_kernel(
    const u16* __restrict__ qkv, const u16* __restrict__ vt,
    float* __restrict__ Op0, float* __restrict__ Op1,
    float* __restrict__ lpart) {
  const int bh = blockIdx.x;          // b*16 + nh
  const int qt = blockIdx.y;          // 0..15
  const int kz = blockIdx.z;          // 0..1
  const int b = bh >> 4, nh = bh & 15;
  const int tid = threadIdx.x;
  const int w = tid >> 6, lane = tid & 63;
  const int l32 = lane & 31, hi = lane >> 5;
  const float c2 = 0.04508422f;       // log2(e)/sqrt(1024)

  __shared__ u16 KS[64][64];          // K tile [key][d], chunk-swizzled
  __shared__ u16 VS[64][64];          // V^T tile [d][key], chunk-swizzled

  const size_t rs = 3072;
  const u16* qbase = qkv + (size_t)b * 2048 * rs + nh * 64;
  const u16* kbase = qbase + 1024;
  const u16* vbase = vt + (size_t)bh * 64 * 2048;
  const int q0 = qt * 128;
  const int k0beg = kz * 1024;

  // Q fragments to registers, pre-scaled by c2.
  bf16x8 aq[4];
  {
    const u16* qrow = qbase + (size_t)(q0 + w * 32 + l32) * rs + hi * 8;
#pragma unroll
    for (int ds = 0; ds < 4; ++ds) {
      u32x4 v = *(const u32x4*)(qrow + ds * 16);
      u16 ti[8], to[8];
      *(u32x4*)ti = v;
#pragma unroll
      for (int j = 0; j < 8; ++j) to[j] = f2b(b2f(ti[j]) * c2);
      u32x4 pk = *(u32x4*)to;
      aq[ds] = __builtin_bit_cast(bf16x8, pk);
    }
  }

  f32x16 Oacc[2];
#pragma unroll
  for (int dn = 0; dn < 2; ++dn)
#pragma unroll
    for (int i = 0; i < 16; ++i) Oacc[dn][i] = 0.f;
  float ls[4] = {0.f, 0.f, 0.f, 0.f};

  // staging map: lane l -> row (l>>3), 16B chunk (l&7) ^ (row&7)  (XOR swz)
  const int srow = lane >> 3;                       // 0..7
  const int scol = ((lane & 7) ^ srow) << 3;        // u16 units, swizzled

#pragma unroll 1
  for (int t = 0; t < 16; ++t) {
    const int k0 = k0beg + t * 64;
    __syncthreads();                  // all waves done with prev tile
    gld_lds16(kbase + (size_t)(k0 + w * 16 + srow) * rs + scol,       &KS[w * 16][0]);
    gld_lds16(kbase + (size_t)(k0 + w * 16 + 8 + srow) * rs + scol,   &KS[w * 16 + 8][0]);
    gld_lds16(vbase + (size_t)(w * 16 + srow) * 2048 + k0 + scol,     &VS[w * 16][0]);
    gld_lds16(vbase + (size_t)(w * 16 + 8 + srow) * 2048 + k0 + scol, &VS[w * 16 + 8][0]);
    __syncthreads();                  // barrier drains vmcnt -> DMA visible

    // S^T = K . Q^T : lane holds S^T[key = 32*jt + crow(r,hi)][query = l32]
    f32x16 S[2];
#pragma unroll
    for (int jt = 0; jt < 2; ++jt)
#pragma unroll
      for (int i = 0; i < 16; ++i) S[jt][i] = 0.f;
#pragma unroll
    for (int jt = 0; jt < 2; ++jt) {
      const int krow = jt * 32 + l32;
#pragma unroll
      for (int ds = 0; ds < 4; ++ds) {
        bf16x8 kv = *(const bf16x8*)&KS[krow][((2 * ds + hi) ^ (krow & 7)) << 3];
        S[jt] = __builtin_amdgcn_mfma_f32_32x32x16_bf16(kv, aq[ds], S[jt], 0, 0, 0);
      }
    }

    // p = exp2(S^T); build PV A-fragments in-register.
    bf16x8 pa[4];
#pragma unroll
    for (int jt = 0; jt < 2; ++jt) {
      float p[16];
#pragma unroll
      for (int r = 0; r < 16; ++r) {
        p[r] = exp2f(S[jt][r]);
        ls[r & 3] += p[r];
      }
#pragma unroll
      for (int bq = 0; bq < 2; ++bq) {
        u32 x0 = cvtpk(p[8 * bq + 0], p[8 * bq + 1]);
        u32 y0 = cvtpk(p[8 * bq + 4], p[8 * bq + 5]);
        u32 x1 = cvtpk(p[8 * bq + 2], p[8 * bq + 3]);
        u32 y1 = cvtpk(p[8 * bq + 6], p[8 * bq + 7]);
        asm("v_permlane32_swap_b32 %0, %1" : "+v"(x0), "+v"(y0));
        asm("v_permlane32_swap_b32 %0, %1" : "+v"(x1), "+v"(y1));
        u32x4 dw = {x0, x1, y0, y1};  // keys {0,1},{2,3},{4,5},{6,7} (+8hi)
        pa[2 * jt + bq] = __builtin_bit_cast(bf16x8, dw);
      }
    }

    // O += P V : lane holds O[query = crow(r,hi)][d = dn*32 + l32]
#pragma unroll
    for (int dn = 0; dn < 2; ++dn) {
      const int vrow = dn * 32 + l32;
#pragma unroll
      for (int ks = 0; ks < 4; ++ks) {
        bf16x8 vv = *(const bf16x8*)&VS[vrow][((2 * ks + hi) ^ (vrow & 7)) << 3];
        Oacc[dn] = __builtin_amdgcn_mfma_f32_32x32x16_bf16(pa[ks], vv, Oacc[dn], 0, 0, 0);
      }
    }
  }

  // l: per-lane partial covers this hi's keys; add partner half (lane^32)
  float lsum = (ls[0] + ls[1]) + (ls[2] + ls[3]);
  const float ltot = lsum + __shfl_xor(lsum, 32);

  float* opart = kz ? Op1 : Op0;
  float* obase = opart + (size_t)b * 2048 * 1024 + (size_t)nh * 64;
  float* lbase = lpart + (size_t)kz * 4096 * 16 + (size_t)b * 2048 * 16 + nh;
#pragma unroll
  for (int r = 0; r < 16; ++r) {
    const int qrow = q0 + w * 32 + (r & 3) + 8 * (r >> 2) + 4 * hi;
#pragma unroll
    for (int dn = 0; dn < 2; ++dn)
      obase[(size_t)qrow * 1024 + dn * 32 + l32] = Oacc[dn][r];
  }
  if (lane < 32) lbase[(size_t)(q0 + w * 32 + l32) * 16] = ltot;
}

// ---------------------------------------------------------------------------
// x1 = xres + LN((O0+O1)/(l0+l1))*g + b ; writes fp32 + bf16.
// Wave-per-row: grid 1024 x 4 waves; lane holds 4 stride-64 float4s; pure
// shfl_xor reduce (no LDS/barrier).
__global__ __launch_bounds__(256) void ln_attn_kernel(
    const float* __restrict__ O0, const float* __restrict__ O1,
    const float* __restrict__ l0, const float* __restrict__ l1,
    const float* __restrict__ xres, const float* __restrict__ g,
    const float* __restrict__ bb, float* __restrict__ outf,
    u16* __restrict__ outb) {
  const int w = threadIdx.x >> 6, lane = threadIdx.x & 63;
  const int row = blockIdx.x * 4 + w;
  const float4* o0r = (const float4*)(O0 + (size_t)row * 1024);
  const float4* o1r = (const float4*)(O1 + (size_t)row * 1024);
  const float* lp0 = l0 + row * 16;
  const float* lp1 = l1 + row * 16;

  float4 v[4];
  float s = 0.f, s2 = 0.f;
#pragma unroll
  for (int j = 0; j < 4; ++j) {
    const int f = j * 64 + lane;            // float4 index in row (0..255)
    const int head = f >> 4;                // all 4 elems same head
    const float inv = 1.f / (lp0[head] + lp1[head]);
    float4 a0 = o0r[f];
    float4 a1 = o1r[f];
    v[j].x = (a0.x + a1.x) * inv;
    v[j].y = (a0.y + a1.y) * inv;
    v[j].z = (a0.z + a1.z) * inv;
    v[j].w = (a0.w + a1.w) * inv;
    s  += v[j].x + v[j].y + v[j].z + v[j].w;
    s2 += v[j].x * v[j].x + v[j].y * v[j].y + v[j].z * v[j].z + v[j].w * v[j].w;
  }
#pragma unroll
  for (int off = 32; off > 0; off >>= 1) {
    s += __shfl_xor(s, off);
    s2 += __shfl_xor(s2, off);
  }
  const float mu = s * (1.f / 1024.f);
  const float var = s2 * (1.f / 1024.f) - mu * mu;
  const float rstd = rsqrtf(var + 1e-5f);

  const float4* xr4 = (const float4*)(xres + (size_t)row * 1024);
  float4* of4 = (float4*)(outf + (size_t)row * 1024);
  u16x4* ob4 = (u16x4*)(outb + (size_t)row * 1024);
#pragma unroll
  for (int j = 0; j < 4; ++j) {
    const int f = j * 64 + lane;
    float4 xr = xr4[f];
    float4 gv = ((const float4*)g)[f];
    float4 bv = ((const float4*)bb)[f];
    float4 o;
    o.x = xr.x + (v[j].x - mu) * rstd * gv.x + bv.x;
    o.y = xr.y + (v[j].y - mu) * rstd * gv.y + bv.y;
    o.z = xr.z + (v[j].z - mu) * rstd * gv.z + bv.z;
    o.w = xr.w + (v[j].w - mu) * rstd * gv.w + bv.w;
    of4[f] = o;
    u16x4 ob = { f2b(o.x), f2b(o.y), f2b(o.z), f2b(o.w) };
    ob4[f] = ob;
  }
}

// ---------------------------------------------------------------------------
// out = xres + LN(p0+p1+p2+p3 + bias)*g + b  (FFN2 split-K combine), fp32 out.
// Wave-per-row (same structure as ln_attn).
__global__ __launch_bounds__(256) void ln_ffn_kernel(
    const u16* __restrict__ p0, const u16* __restrict__ p1,
    const u16* __restrict__ p2, const u16* __restrict__ p3,
    const float* __restrict__ bias, const float* __restrict__ xres,
    const float* __restrict__ g, const float* __restrict__ bb,
    float* __restrict__ outf) {
  const int w = threadIdx.x >> 6, lane = threadIdx.x & 63;
  const int row = blockIdx.x * 4 + w;
  const u16x4* p0r = (const u16x4*)(p0 + (size_t)row * 1024);
  const u16x4* p1r = (const u16x4*)(p1 + (size_t)row * 1024);
  const u16x4* p2r = (const u16x4*)(p2 + (size_t)row * 1024);
  const u16x4* p3r = (const u16x4*)(p3 + (size_t)row * 1024);

  float4 v[4];
  float s = 0.f, s2 = 0.f;
#pragma unroll
  for (int j = 0; j < 4; ++j) {
    const int f = j * 64 + lane;
    u16x4 a0 = p0r[f];
    u16x4 a1 = p1r[f];
    u16x4 a2 = p2r[f];
    u16x4 a3 = p3r[f];
    float4 bv4 = ((const float4*)bias)[f];
    v[j].x = (b2f(a0[0]) + b2f(a1[0])) + (b2f(a2[0]) + b2f(a3[0])) + bv4.x;
    v[j].y = (b2f(a0[1]) + b2f(a1[1])) + (b2f(a2[1]) + b2f(a3[1])) + bv4.y;
    v[j].z = (b2f(a0[2]) + b2f(a1[2])) + (b2f(a2[2]) + b2f(a3[2])) + bv4.z;
    v[j].w = (b2f(a0[3]) + b2f(a1[3])) + (b2f(a2[3]) + b2f(a3[3])) + bv4.w;
    s  += v[j].x + v[j].y + v[j].z + v[j].w;
    s2 += v[j].x * v[j].x + v[j].y * v[j].y + v[j].z * v[j].z + v[j].w * v[j].w;
  }
#pragma unroll
  for (int off = 32; off > 0; off >>= 1) {
    s += __shfl_xor(s, off);
    s2 += __shfl_xor(s2, off);
  }
  const float mu = s * (1.f / 1024.f);
  const float var = s2 * (1.f / 1024.f) - mu * mu;
  const float rstd = rsqrtf(var + 1e-5f);

  const float4* xr4 = (const float4*)(xres + (size_t)row * 1024);
  float4* of4 = (float4*)(outf + (size_t)row * 1024);
#pragma unroll
  for (int j = 0; j < 4; ++j) {
    const int f = j * 64 + lane;
    float4 xr = xr4[f];
    float4 gv = ((const float4*)g)[f];
    float4 bv = ((const float4*)bb)[f];
    float4 o;
    o.x = xr.x + (v[j].x - mu) * rstd * gv.x + bv.x;
    o.y = xr.y + (v[j].y - mu) * rstd * gv.y + bv.y;
    o.z = xr.z + (v[j].z - mu) * rstd * gv.z + bv.z;
    o.w = xr.w + (v[j].w - mu) * rstd * gv.w + bv.w;
    of4[f] = o;
  }
}

// ---------------------------------------------------------------------------
extern "C" void kernel_launch(void* const* d_in, const int* in_sizes, int n_in,
                              void* d_out, int out_size, void* d_ws, size_t ws_size,
                              hipStream_t stream) {
  const float* x     = (const float*)d_in[0];
  const float* w_qkv = (const float*)d_in[1];
  const float* ln1_g = (const float*)d_in[2];
  const float* ln1_b = (const float*)d_in[3];
  const float* w1    = (const float*)d_in[4];
  const float* b1    = (const float*)d_in[5];
  const float* w2    = (const float*)d_in[6];
  const float* b2    = (const float*)d_in[7];
  const float* ln2_g = (const float*)d_in[8];
  const float* ln2_b = (const float*)d_in[9];
  float* out = (float*)d_out;
  char* ws = (char*)d_ws;

  // workspace (lifetime-aliased; max end = 98,566,144 B):
  u16*   xb    = (u16*)(ws + 0);              // [0,8.4M)     dead after qkv gemm
  u16*   wqkvT = (u16*)(ws + 8388608);        // [8.4,14.7M)  dead after qkv gemm
  u16*   qkvb  = (u16*)(ws + 31457280);       // [31.5,56.6M) dead after attn
  u16*   vT    = (u16*)(ws + 56623104);       // [56.6,73.4M) dead after attn
  float* Op0   = (float*)(ws + 0);            // [0,16.8M)    attn partial 0 (over dead xb/wqkvT)
  float* Op1   = (float*)(ws + 73400320);     // [73.4,90.2M) attn partial 1
  float* lp    = (float*)(ws + 90177536);     // [90.2,90.7M) l partials (2x256KB)
  float* x1    = (float*)(ws + 31457280);     // [31.5,48.2M) over dead qkvb (after attn)
  u16*   x1b   = (u16*)(ws + 48234496);       // [48.2,56.6M) over dead qkvb; dead after FFN1
  u16*   w1T   = (u16*)(ws + 14680064);       // [14.7,23.1M) written after LN1 (over dead Op0)
  u16*   w2T   = (u16*)(ws + 23068672);       // [23.1,31.5M) written after LN1
  u16*   h1    = (u16*)(ws + 56623104);       // [56.6,90.2M) over dead vT+Op1
  u16*   fp0   = (u16*)(ws + 0);              // FFN2 partials (over dead Op0/lp/x1b)
  u16*   fp1   = (u16*)(ws + 8388608);
  u16*   fp2   = (u16*)(ws + 48234496);
  u16*   fp3   = (u16*)(ws + 90177536);

  // prep1: x->bf16 convert + wqkv transpose (fused, 4096+3072 blocks)
  prep1_kernel<<<7168, 256, 0, stream>>>(x, xb, w_qkv, wqkvT);

  // qkv: M=4096 N=3072 K=1024 -> 256x192 tiles, 16x16 = 256 blocks (full fill)
  gemm_qkv_kernel<<<256, 512, 0, stream>>>(xb, wqkvT, qkvb);
  transpose_v_kernel<<<dim3(32, 32), 256, 0, stream>>>(qkvb, vT);
  attn_kernel<<<dim3(32, 16, 2), 256, 0, stream>>>(qkvb, vT, Op0, Op1, lp);

  ln_attn_kernel<<<1024, 256, 0, stream>>>(
      Op0, Op1, lp, lp + 4096 * 16, x, ln1_g, ln1_b, x1, x1b);

  // prep2: w1 + w2 transposes (fused, 4096+4096 blocks)
  prep2_kernel<<<8192, 256, 0, stream>>>(w1, w1T, w2, w2T);

  // FFN1: M=4096 N=4096 K=1024 -> 256 blocks
  gemm256_kernel<<<dim3(256, 1), 512, 0, stream>>>(
      x1b, w1T, b1, h1, 4096, 4096, 1024, 1,
      nullptr, nullptr, nullptr);
  // FFN2: M=4096 N=1024 K=4096, split-K=4 -> 64x4 blocks
  gemm256_kernel<<<dim3(64, 4), 512, 0, stream>>>(
      h1, w2T, nullptr, fp0, 4096, 1024, 4096, 0,
      fp1, fp2, fp3);

  ln_ffn_kernel<<<1024, 256, 0, stream>>>(
      fp0, fp1, fp2, fp3, b2, x1, ln2_g, ln2_b, out);
}

// Round 10
// 303.921 us; speedup vs baseline: 1.0650x; 1.0148x over previous
//
#include <hip/hip_runtime.h>

// ---------------------------------------------------------------------------
// TransformerBlock: x:[2,2048,1024] fp32
//   qkv = x @ w_qkv;  attention (scale 1/sqrt(1024));  x = x + LN(attn_out)
//   ff  = relu(x@w1+b1)@w2+b2;  out = x + LN(ff)
// R17: GEMM occupancy 2 -> 4 waves/SIMD. All prior GEMMs: 512 thr, ~190
//     VGPR, >=84KB LDS -> 1 block/CU, 2 waves/SIMD (same starvation attn
//     showed; explains why R11/R12/R15 schedules tied). New: same 256^2
//     tile + R12 3-buffer/1-barrier/counted-vmcnt ledger spread over 16
//     waves (1024 thr, 4Mx4N): acc[4][4]=64 VGPR, launch_bounds(1024)
//     forces VGPR<=128 -> 4 waves/SIMD. Staging: exactly 1 A + 1 B issue
//     per wave per tile (vmcnt(2); qkv BN=192: B by waves 0-11, vmcnt 2/1).
//     Per tile/wave: 8 ds_read_b128, 16 MFMA. attn=R8, LN/preps=R14,
//     qkv full-fill BN=192 grid=256 (R16) all frozen.
// ---------------------------------------------------------------------------

typedef unsigned short u16;
typedef unsigned int u32;
typedef __bf16 bf16x8 __attribute__((ext_vector_type(8)));
typedef float f32x4 __attribute__((ext_vector_type(4)));
typedef float f32x16 __attribute__((ext_vector_type(16)));
typedef u32 u32x4 __attribute__((ext_vector_type(4)));
typedef u16 u16x4 __attribute__((ext_vector_type(4)));

__device__ __forceinline__ u16 f2b(float f) {
  u32 u = __builtin_bit_cast(u32, f);
  u += 0x7fffu + ((u >> 16) & 1u);       // RNE
  return (u16)(u >> 16);
}
__device__ __forceinline__ float b2f(u16 u) {
  return __builtin_bit_cast(float, (u32)u << 16);
}

// pack 2 fp32 -> 1 dword of 2 bf16 (RNE), lo in low half
__device__ __forceinline__ u32 cvtpk(float lo, float hi) {
  u32 r;
  asm("v_cvt_pk_bf16_f32 %0, %1, %2" : "=v"(r) : "v"(lo), "v"(hi));
  return r;
}

// async global->LDS DMA, 16B per lane. LDS dest = wave-uniform base + lane*16.
__device__ __forceinline__ void gld_lds16(const u16* g, u16* l) {
  __builtin_amdgcn_global_load_lds(
      (const __attribute__((address_space(1))) u32*)g,
      (__attribute__((address_space(3))) u32*)l, 16, 0, 0);
}

// ---------------------------------------------------------------------------
// 32x32 fp32->bf16 transpose tile helper (whole block must call).
__device__ __forceinline__ void transpose32(
    const float* __restrict__ in, u16* __restrict__ out, int R, int C,
    int bx, int by, float (*tile)[33], int tid) {
  const int cb = bx * 32, rb = by * 32;
  const int c = tid & 31;
  const int r0 = tid >> 5;
#pragma unroll
  for (int rr = 0; rr < 32; rr += 8)
    tile[r0 + rr][c] = in[(size_t)(rb + r0 + rr) * C + cb + c];
  __syncthreads();
#pragma unroll
  for (int rr = 0; rr < 32; rr += 8)
    out[(size_t)(cb + r0 + rr) * R + rb + c] = f2b(tile[c][r0 + rr]);
}

// prep1: blocks [0,4096): x fp32->bf16 convert. blocks [4096,7168): wqkv^T.
__global__ __launch_bounds__(256) void prep1_kernel(
    const float* __restrict__ x, u16* __restrict__ xb,
    const float* __restrict__ w_qkv, u16* __restrict__ wqkvT) {
  __shared__ float tile[32][33];
  const int bid = blockIdx.x;
  const int tid = threadIdx.x;
  if (bid < 4096) {
    const int idx = bid * 256 + tid;
    float4 v = ((const float4*)x)[idx];
    u16x4 o = { f2b(v.x), f2b(v.y), f2b(v.z), f2b(v.w) };
    ((u16x4*)xb)[idx] = o;
  } else {
    const int t = bid - 4096;
    transpose32(w_qkv, wqkvT, 1024, 3072, t % 96, t / 96, tile, tid);
  }
}

// prep2: blocks [0,4096): w1^T (1024x4096). blocks [4096,8192): w2^T (4096x1024).
__global__ __launch_bounds__(256) void prep2_kernel(
    const float* __restrict__ w1, u16* __restrict__ w1T,
    const float* __restrict__ w2, u16* __restrict__ w2T) {
  __shared__ float tile[32][33];
  const int bid = blockIdx.x;
  const int tid = threadIdx.x;
  if (bid < 4096) {
    transpose32(w1, w1T, 1024, 4096, bid % 128, bid / 128, tile, tid);
  } else {
    const int t = bid - 4096;
    transpose32(w2, w2T, 4096, 1024, t % 32, t / 32, tile, tid);
  }
}

// V part of qkv [s][d] -> vt[bh][d][s]  (bf16 copy-transpose, 64x64 tiles)
__global__ __launch_bounds__(256) void transpose_v_kernel(
    const u16* __restrict__ qkv, u16* __restrict__ vt) {
  __shared__ u16 t[64][70];
  const int bh = blockIdx.x, st = blockIdx.y;
  const int b = bh >> 4, nh = bh & 15;
  const int s0 = st * 64;
  const int r = threadIdx.x >> 3, c = (threadIdx.x & 7) << 3;
  const u16* src = qkv + (size_t)(b * 2048 + s0) * 3072 + 2048 + nh * 64;
#pragma unroll
  for (int rr = 0; rr < 64; rr += 32)
    *(u32x4*)&t[r + rr][c] = *(const u32x4*)(src + (size_t)(r + rr) * 3072 + c);
  __syncthreads();
  u16* dst = vt + ((size_t)bh * 64) * 2048 + s0;
#pragma unroll
  for (int rr = 0; rr < 64; rr += 32) {
    const int d = r + rr;
    u16 tmp[8];
#pragma unroll
    for (int j = 0; j < 8; ++j) tmp[j] = t[c + j][d];
    *(u32x4*)(dst + (size_t)d * 2048 + c) = *(u32x4*)tmp;
  }
}

// ---------------------------------------------------------------------------
// C[M,N] = A[M,K](bf16) @ Bt[N,K](bf16)^T, fp32 accum, bf16 out.
// 256x256 tile, BK=32, 16 waves (4Mx4N, 1024 thr), 3 LDS buffers (96KB),
// one barrier/tile, counted vmcnt(2) (1 A-issue + 1 B-issue per wave/tile).
// K-per-block hardcoded 1024 (32 tiles); split-K via gridDim.y (z*1024 off).
// Requires M%256==0, N%256==0, gridDim.x%8==0.
#define GT16(BUF, SBUF, T2, VM)                                               \
  {                                                                           \
    const u16(*Ab)[32] = As[BUF];                                             \
    const u16(*Bb)[32] = Bs[BUF];                                             \
    bf16x8 af[4], bfr[4];                                                     \
    _Pragma("unroll") for (int nr = 0; nr < 4; ++nr)                          \
        bfr[nr] = *(const bf16x8*)&Bb[wn * 64 + nr * 16 + l16][cRd];          \
    _Pragma("unroll") for (int mr = 0; mr < 4; ++mr)                          \
        af[mr] = *(const bf16x8*)&Ab[wm * 64 + mr * 16 + l16][cRd];           \
    if ((T2) >= 0) {                                                          \
      gld_lds16(Ag + (size_t)(T2) * 32, &As[SBUF][w * 16][0]);                \
      gld_lds16(Bg + (size_t)(T2) * 32, &Bs[SBUF][w * 16][0]);                \
    }                                                                         \
    asm volatile("s_waitcnt lgkmcnt(0)" ::: "memory");                        \
    __builtin_amdgcn_sched_barrier(0);                                        \
    __builtin_amdgcn_s_setprio(1);                                            \
    _Pragma("unroll") for (int mr = 0; mr < 4; ++mr)                          \
        _Pragma("unroll") for (int nr = 0; nr < 4; ++nr)                      \
            acc[mr][nr] = __builtin_amdgcn_mfma_f32_16x16x32_bf16(            \
                af[mr], bfr[nr], acc[mr][nr], 0, 0, 0);                       \
    __builtin_amdgcn_s_setprio(0);                                            \
    if ((VM) == 2) asm volatile("s_waitcnt vmcnt(2)" ::: "memory");           \
    else if ((VM) == 0) asm volatile("s_waitcnt vmcnt(0)" ::: "memory");      \
    if ((VM) >= 0) __builtin_amdgcn_s_barrier();                              \
  }

__global__ __launch_bounds__(1024) void gemm256_kernel(
    const u16* __restrict__ A, const u16* __restrict__ Bt,
    const float* __restrict__ bias, u16* __restrict__ Cb,
    int M, int N, int K, int relu,
    u16* __restrict__ Cb1, u16* __restrict__ Cb2, u16* __restrict__ Cb3) {
  const int nN = N >> 8;
  const int lin = (blockIdx.x & 7) * ((int)gridDim.x >> 3) + (blockIdx.x >> 3);
  const int m0 = (lin / nN) << 8;
  const int n0 = (lin % nN) << 8;
  const int z = blockIdx.y;
  if (z == 1) Cb = Cb1; else if (z == 2) Cb = Cb2; else if (z == 3) Cb = Cb3;

  const int tid = threadIdx.x;
  const int w = tid >> 6, lane = tid & 63;
  const int quad = lane >> 4, l16 = lane & 15;
  const int wm = w >> 2, wn = w & 3;    // wave owns rows wm*64.., cols wn*64..

  __shared__ u16 As[3][256][32];        // 48KB
  __shared__ u16 Bs[3][256][32];        // 48KB

  f32x4 acc[4][4];
#pragma unroll
  for (int i = 0; i < 4; ++i)
#pragma unroll
    for (int j = 0; j < 4; ++j) acc[i][j] = {0.f, 0.f, 0.f, 0.f};

  // staging: wave w covers rows w*16+(l>>2); pre-swizzled chunk (l&3)^(srow&3)
  const int srow = lane >> 2;                               // 0..15
  const int scol = (((lane & 3) ^ (srow & 3)) << 3);        // u16 units
  const u16* Ag = A + (size_t)(m0 + w * 16 + srow) * K + (size_t)z * 1024 + scol;
  const u16* Bg = Bt + (size_t)(n0 + w * 16 + srow) * K + (size_t)z * 1024 + scol;

  // fragment-read swizzled chunk
  const int cRd = ((quad ^ (l16 & 3)) << 3);                // u16 units

  // prologue: stage k-tiles 0 and 1 (A0,B0,A1,B1); vmcnt(2) -> tile 0 resident
  gld_lds16(Ag,      &As[0][w * 16][0]);
  gld_lds16(Bg,      &Bs[0][w * 16][0]);
  gld_lds16(Ag + 32, &As[1][w * 16][0]);
  gld_lds16(Bg + 32, &Bs[1][w * 16][0]);
  asm volatile("s_waitcnt vmcnt(2)" ::: "memory");
  __builtin_amdgcn_s_barrier();

  for (int tt = 0; tt < 10; ++tt) {
    const int t = tt * 3;
    GT16(0, 2, t + 2, 2)
    GT16(1, 0, t + 3, 2)
    GT16(2, 1, t + 4, 2)
  }
  GT16(0, 0, -1, 0)    // tile 30: drain tile 31's DMAs
  GT16(1, 0, -1, -1)   // tile 31

  // epilogue: wave writes 64 rows x 64 cols
#pragma unroll
  for (int mr = 0; mr < 4; ++mr) {
    const int row = m0 + wm * 64 + mr * 16 + quad * 4;
#pragma unroll
    for (int nr = 0; nr < 4; ++nr) {
      const int col = n0 + wn * 64 + nr * 16 + l16;
      const float bv = bias ? bias[col] : 0.f;
#pragma unroll
      for (int r = 0; r < 4; ++r) {
        float v = acc[mr][nr][r] + bv;
        if (relu) v = fmaxf(v, 0.f);
        Cb[(size_t)(row + r) * N + col] = f2b(v);
      }
    }
  }
}

// ---------------------------------------------------------------------------
// qkv GEMM: C[4096,3072] = A[4096,1024] @ Bt[3072,1024]^T, bf16 out.
// BM=256 x BN=192 -> 256 blocks (full CU fill, R16). 16 waves (1024 thr):
// per wave 64 rows x 48 cols, acc[4][3]. B (192 rows) staged by waves 0-11
// only -> wave-class vmcnt: w<12 keeps 2/tile in flight, w>=12 keeps 1.
#define QVMC                                                                  \
  if (w < 12) { asm volatile("s_waitcnt vmcnt(2)" ::: "memory"); }            \
  else        { asm volatile("s_waitcnt vmcnt(1)" ::: "memory"); }
#define QGT16(BUF, SBUF, T2, VM)                                              \
  {                                                                           \
    const u16(*Ab)[32] = As[BUF];                                             \
    const u16(*Bb)[32] = Bs[BUF];                                             \
    bf16x8 af[4], bfr[3];                                                     \
    _Pragma("unroll") for (int nr = 0; nr < 3; ++nr)                          \
        bfr[nr] = *(const bf16x8*)&Bb[wn * 48 + nr * 16 + l16][cRd];          \
    _Pragma("unroll") for (int mr = 0; mr < 4; ++mr)                          \
        af[mr] = *(const bf16x8*)&Ab[wm * 64 + mr * 16 + l16][cRd];           \
    if ((T2) >= 0) {                                                          \
      gld_lds16(Ag + (size_t)(T2) * 32, &As[SBUF][w * 16][0]);                \
      if (w < 12)                                                             \
        gld_lds16(Bg + (size_t)(T2) * 32, &Bs[SBUF][w * 16][0]);              \
    }                                                                         \
    asm volatile("s_waitcnt lgkmcnt(0)" ::: "memory");                        \
    __builtin_amdgcn_sched_barrier(0);                                        \
    __builtin_amdgcn_s_setprio(1);                                            \
    _Pragma("unroll") for (int mr = 0; mr < 4; ++mr)                          \
        _Pragma("unroll") for (int nr = 0; nr < 3; ++nr)                      \
            acc[mr][nr] = __builtin_amdgcn_mfma_f32_16x16x32_bf16(            \
                af[mr], bfr[nr], acc[mr][nr], 0, 0, 0);                       \
    __builtin_amdgcn_s_setprio(0);                                            \
    if ((VM) == 2) { QVMC }                                                   \
    else if ((VM) == 0) asm volatile("s_waitcnt vmcnt(0)" ::: "memory");      \
    if ((VM) >= 0) __builtin_amdgcn_s_barrier();                              \
  }

__global__ __launch_bounds__(1024) void gemm_qkv_kernel(
    const u16* __restrict__ A, const u16* __restrict__ Bt,
    u16* __restrict__ Cb) {
  const int K = 1024, N = 3072;
  // XCD-chunked bijective swizzle over 256 blocks (16 M-panels x 16 N-panels)
  const int lin = (blockIdx.x & 7) * 32 + (blockIdx.x >> 3);
  const int m0 = (lin >> 4) << 8;          // 256-row panel
  const int n0 = (lin & 15) * 192;         // 192-col panel

  const int tid = threadIdx.x;
  const int w = tid >> 6, lane = tid & 63;
  const int quad = lane >> 4, l16 = lane & 15;
  const int wm = w >> 2, wn = w & 3;

  __shared__ u16 As[3][256][32];           // 48KB
  __shared__ u16 Bs[3][192][32];           // 36KB

  f32x4 acc[4][3];
#pragma unroll
  for (int i = 0; i < 4; ++i)
#pragma unroll
    for (int j = 0; j < 3; ++j) acc[i][j] = {0.f, 0.f, 0.f, 0.f};

  const int srow = lane >> 2;                               // 0..15
  const int scol = (((lane & 3) ^ (srow & 3)) << 3);        // u16 units
  const u16* Ag = A + (size_t)(m0 + w * 16 + srow) * K + scol;
  const u16* Bg = Bt + (size_t)(n0 + w * 16 + srow) * K + scol;   // w<12 only

  const int cRd = ((quad ^ (l16 & 3)) << 3);                // u16 units

  // prologue: stage k-tiles 0 and 1 (A0,[B0],A1,[B1])
  gld_lds16(Ag,      &As[0][w * 16][0]);
  if (w < 12) gld_lds16(Bg,      &Bs[0][w * 16][0]);
  gld_lds16(Ag + 32, &As[1][w * 16][0]);
  if (w < 12) gld_lds16(Bg + 32, &Bs[1][w * 16][0]);
  QVMC
  __builtin_amdgcn_s_barrier();

  for (int tt = 0; tt < 10; ++tt) {
    const int t = tt * 3;
    QGT16(0, 2, t + 2, 2)
    QGT16(1, 0, t + 3, 2)
    QGT16(2, 1, t + 4, 2)
  }
  QGT16(0, 0, -1, 0)    // tile 30: drain
  QGT16(1, 0, -1, -1)   // tile 31

  // epilogue: wave writes 64 rows x 48 cols
#pragma unroll
  for (int mr = 0; mr < 4; ++mr) {
    const int row = m0 + wm * 64 + mr * 16 + quad * 4;
#pragma unroll
    for (int nr = 0; nr < 3; ++nr) {
      const int col = n0 + wn * 48 + nr * 16 + l16;
#pragma unroll
      for (int r = 0; r < 4; ++r)
        Cb[(size_t)(row + r) * N + col] = f2b(acc[mr][nr][r]);
    }
  }
}

// ---------------------------------------------------------------------------
// Flash attention (R8, best measured), fixed-max softmax, key-split kz in {0,1}.
// Block = (bh, 128 q-rows, 1024-key range); 4 waves x 32 q-rows.
// 32x32x16 MFMA, swapped QK^T (S^T = K.Q^T): lane owns query = lane&31.
// P fragments built in-register via cvt_pk_bf16 + permlane32_swap.
// Writes UNNORMALIZED O partial (fp32) + l partial; LN1 combines.
__global__ __launch_bounds__(256, 4) void attn_kernel(
    const u16* __restrict__ qkv, const u16* __restrict__ vt,
    float* __restrict__ Op0, float* __restrict__ Op1,
    float* __restrict__ lpart) {
  const int bh = blockIdx.x;          // b*16 + nh
  const int qt = blockIdx.y;          // 0..15
  const int kz = blockIdx.z;          // 0..1
  const int b = bh >> 4, nh = bh & 15;
  const int tid = threadIdx.x;
  const int w = tid >> 6, lane = tid & 63;
  const int l32 = lane & 31, hi = lane >> 5;
  const float c2 = 0.04508422f;       // log2(e)/sqrt(1024)

  __shared__ u16 KS[64][64];          // K tile [key][d], chunk-swizzled
  __shared__ u16 VS[64][64];          // V^T tile [d][key], chunk-swizzled

  const size_t rs = 3072;
  const u16* qbase = qkv + (size_t)b * 2048 * rs + nh * 64;
  const u16* kbase = qbase + 1024;
  const u16* vbase = vt + (size_t)bh * 64 * 2048;
  const int q0 = qt * 128;
  const int k0beg = kz * 1024;

  // Q fragments to registers, pre-scaled by c2.
  bf16x8 aq[4];
  {
    const u16* qrow = qbase + (size_t)(q0 + w * 32 + l32) * rs + hi * 8;
#pragma unroll
    for (int ds = 0; ds < 4; ++ds) {
      u32x4 v = *(const u32x4*)(qrow + ds * 16);
      u16 ti[8], to[8];
      *(u32x4*)ti = v;
#pragma unroll
      for (int j = 0; j < 8; ++j) to[j] = f2b(b2f(ti[j]) * c2);
      u32x4 pk = *(u32x4*)to;
      aq[ds] = __builtin_bit_cast(bf16x8, pk);
    }
  }

  f32x16 Oacc[2];
#pragma unroll
  for (int dn = 0; dn < 2; ++dn)
#pragma unroll
    for (int i = 0; i < 16; ++i) Oacc[dn][i] = 0.f;
  float ls[4] = {0.f, 0.f, 0.f, 0.f};

  // staging map: lane l -> row (l>>3), 16B chunk (l&7) ^ (row&7)  (XOR swz)
  const int srow = lane >> 3;                       // 0..7
  const int scol = ((lane & 7) ^ srow) << 3;        // u16 units, swizzled

#pragma unroll 1
  for (int t = 0; t < 16; ++t) {
    const int k0 = k0beg + t * 64;
    __syncthreads();                  // all waves done with prev tile
    gld_lds16(kbase + (size_t)(k0 + w * 16 + srow) * rs + scol,       &KS[w * 16][0]);
    gld_lds16(kbase + (size_t)(k0 + w * 16 + 8 + srow) * rs + scol,   &KS[w * 16 + 8][0]);
    gld_lds16(vbase + (size_t)(w * 16 + srow) * 2048 + k0 + scol,     &VS[w * 16][0]);
    gld_lds16(vbase + (size_t)(w * 16 + 8 + srow) * 2048 + k0 + scol, &VS[w * 16 + 8][0]);
    __syncthreads();                  // barrier drains vmcnt -> DMA visible

    // S^T = K . Q^T : lane holds S^T[key = 32*jt + crow(r,hi)][query = l32]
    f32x16 S[2];
#pragma unroll
    for (int jt = 0; jt < 2; ++jt)
#pragma unroll
      for (int i = 0; i < 16; ++i) S[jt][i] = 0.f;
#pragma unroll
    for (int jt = 0; jt < 2; ++jt) {
      const int krow = jt * 32 + l32;
#pragma unroll
      for (int ds = 0; ds < 4; ++ds) {
        bf16x8 kv = *(const bf16x8*)&KS[krow][((2 * ds + hi) ^ (krow & 7)) << 3];
        S[jt] = __builtin_amdgcn_mfma_f32_32x32x16_bf16(kv, aq[ds], S[jt], 0, 0, 0);
      }
    }

    // p = exp2(S^T); build PV A-fragments in-register.
    bf16x8 pa[4];
#pragma unroll
    for (int jt = 0; jt < 2; ++jt) {
      float p[16];
#pragma unroll
      for (int r = 0; r < 16; ++r) {
        p[r] = exp2f(S[jt][r]);
        ls[r & 3] += p[r];
      }
#pragma unroll
      for (int bq = 0; bq < 2; ++bq) {
        u32 x0 = cvtpk(p[8 * bq + 0], p[8 * bq + 1]);
        u32 y0 = cvtpk(p[8 * bq + 4], p[8 * bq + 5]);
        u32 x1 = cvtpk(p[8 * bq + 2], p[8 * bq + 3]);
        u32 y1 = cvtpk(p[8 * bq + 6], p[8 * bq + 7]);
        asm("v_permlane32_swap_b32 %0, %1" : "+v"(x0), "+v"(y0));
        asm("v_permlane32_swap_b32 %0, %1" : "+v"(x1), "+v"(y1));
        u32x4 dw = {x0, x1, y0, y1};  // keys {0,1},{2,3},{4,5},{6,7} (+8hi)
        pa[2 * jt + bq] = __builtin_bit_cast(bf16x8, dw);
      }
    }

    // O += P V : lane holds O[query = crow(r,hi)][d = dn*32 + l32]
#pragma unroll
    for (int dn = 0; dn < 2; ++dn) {
      const int vrow = dn * 32 + l32;
#pragma unroll
      for (int ks = 0; ks < 4; ++ks) {
        bf16x8 vv = *(const bf16x8*)&VS[vrow][((2 * ks + hi) ^ (vrow & 7)) << 3];
        Oacc[dn] = __builtin_amdgcn_mfma_f32_32x32x16_bf16(pa[ks], vv, Oacc[dn], 0, 0, 0);
      }
    }
  }

  // l: per-lane partial covers this hi's keys; add partner half (lane^32)
  float lsum = (ls[0] + ls[1]) + (ls[2] + ls[3]);
  const float ltot = lsum + __shfl_xor(lsum, 32);

  float* opart = kz ? Op1 : Op0;
  float* obase = opart + (size_t)b * 2048 * 1024 + (size_t)nh * 64;
  float* lbase = lpart + (size_t)kz * 4096 * 16 + (size_t)b * 2048 * 16 + nh;
#pragma unroll
  for (int r = 0; r < 16; ++r) {
    const int qrow = q0 + w * 32 + (r & 3) + 8 * (r >> 2) + 4 * hi;
#pragma unroll
    for (int dn = 0; dn < 2; ++dn)
      obase[(size_t)qrow * 1024 + dn * 32 + l32] = Oacc[dn][r];
  }
  if (lane < 32) lbase[(size_t)(q0 + w * 32 + l32) * 16] = ltot;
}

// ---------------------------------------------------------------------------
// x1 = xres + LN((O0+O1)/(l0+l1))*g + b ; writes fp32 + bf16.
// Wave-per-row: grid 1024 x 4 waves; lane holds 4 stride-64 float4s; pure
// shfl_xor reduce (no LDS/barrier).
__global__ __launch_bounds__(256) void ln_attn_kernel(
    const float* __restrict__ O0, const float* __restrict__ O1,
    const float* __restrict__ l0, const float* __restrict__ l1,
    const float* __restrict__ xres, const float* __restrict__ g,
    const float* __restrict__ bb, float* __restrict__ outf,
    u16* __restrict__ outb) {
  const int w = threadIdx.x >> 6, lane = threadIdx.x & 63;
  const int row = blockIdx.x * 4 + w;
  const float4* o0r = (const float4*)(O0 + (size_t)row * 1024);
  const float4* o1r = (const float4*)(O1 + (size_t)row * 1024);
  const float* lp0 = l0 + row * 16;
  const float* lp1 = l1 + row * 16;

  float4 v[4];
  float s = 0.f, s2 = 0.f;
#pragma unroll
  for (int j = 0; j < 4; ++j) {
    const int f = j * 64 + lane;            // float4 index in row (0..255)
    const int head = f >> 4;                // all 4 elems same head
    const float inv = 1.f / (lp0[head] + lp1[head]);
    float4 a0 = o0r[f];
    float4 a1 = o1r[f];
    v[j].x = (a0.x + a1.x) * inv;
    v[j].y = (a0.y + a1.y) * inv;
    v[j].z = (a0.z + a1.z) * inv;
    v[j].w = (a0.w + a1.w) * inv;
    s  += v[j].x + v[j].y + v[j].z + v[j].w;
    s2 += v[j].x * v[j].x + v[j].y * v[j].y + v[j].z * v[j].z + v[j].w * v[j].w;
  }
#pragma unroll
  for (int off = 32; off > 0; off >>= 1) {
    s += __shfl_xor(s, off);
    s2 += __shfl_xor(s2, off);
  }
  const float mu = s * (1.f / 1024.f);
  const float var = s2 * (1.f / 1024.f) - mu * mu;
  const float rstd = rsqrtf(var + 1e-5f);

  const float4* xr4 = (const float4*)(xres + (size_t)row * 1024);
  float4* of4 = (float4*)(outf + (size_t)row * 1024);
  u16x4* ob4 = (u16x4*)(outb + (size_t)row * 1024);
#pragma unroll
  for (int j = 0; j < 4; ++j) {
    const int f = j * 64 + lane;
    float4 xr = xr4[f];
    float4 gv = ((const float4*)g)[f];
    float4 bv = ((const float4*)bb)[f];
    float4 o;
    o.x = xr.x + (v[j].x - mu) * rstd * gv.x + bv.x;
    o.y = xr.y + (v[j].y - mu) * rstd * gv.y + bv.y;
    o.z = xr.z + (v[j].z - mu) * rstd * gv.z + bv.z;
    o.w = xr.w + (v[j].w - mu) * rstd * gv.w + bv.w;
    of4[f] = o;
    u16x4 ob = { f2b(o.x), f2b(o.y), f2b(o.z), f2b(o.w) };
    ob4[f] = ob;
  }
}

// ---------------------------------------------------------------------------
// out = xres + LN(p0+p1+p2+p3 + bias)*g + b  (FFN2 split-K combine), fp32 out.
// Wave-per-row (same structure as ln_attn).
__global__ __launch_bounds__(256) void ln_ffn_kernel(
    const u16* __restrict__ p0, const u16* __restrict__ p1,
    const u16* __restrict__ p2, const u16* __restrict__ p3,
    const float* __restrict__ bias, const float* __restrict__ xres,
    const float* __restrict__ g, const float* __restrict__ bb,
    float* __restrict__ outf) {
  const int w = threadIdx.x >> 6, lane = threadIdx.x & 63;
  const int row = blockIdx.x * 4 + w;
  const u16x4* p0r = (const u16x4*)(p0 + (size_t)row * 1024);
  const u16x4* p1r = (const u16x4*)(p1 + (size_t)row * 1024);
  const u16x4* p2r = (const u16x4*)(p2 + (size_t)row * 1024);
  const u16x4* p3r = (const u16x4*)(p3 + (size_t)row * 1024);

  float4 v[4];
  float s = 0.f, s2 = 0.f;
#pragma unroll
  for (int j = 0; j < 4; ++j) {
    const int f = j * 64 + lane;
    u16x4 a0 = p0r[f];
    u16x4 a1 = p1r[f];
    u16x4 a2 = p2r[f];
    u16x4 a3 = p3r[f];
    float4 bv4 = ((const float4*)bias)[f];
    v[j].x = (b2f(a0[0]) + b2f(a1[0])) + (b2f(a2[0]) + b2f(a3[0])) + bv4.x;
    v[j].y = (b2f(a0[1]) + b2f(a1[1])) + (b2f(a2[1]) + b2f(a3[1])) + bv4.y;
    v[j].z = (b2f(a0[2]) + b2f(a1[2])) + (b2f(a2[2]) + b2f(a3[2])) + bv4.z;
    v[j].w = (b2f(a0[3]) + b2f(a1[3])) + (b2f(a2[3]) + b2f(a3[3])) + bv4.w;
    s  += v[j].x + v[j].y + v[j].z + v[j].w;
    s2 += v[j].x * v[j].x + v[j].y * v[j].y + v[j].z * v[j].z + v[j].w * v[j].w;
  }
#pragma unroll
  for (int off = 32; off > 0; off >>= 1) {
    s += __shfl_xor(s, off);
    s2 += __shfl_xor(s2, off);
  }
  const float mu = s * (1.f / 1024.f);
  const float var = s2 * (1.f / 1024.f) - mu * mu;
  const float rstd = rsqrtf(var + 1e-5f);

  const float4* xr4 = (const float4*)(xres + (size_t)row * 1024);
  float4* of4 = (float4*)(outf + (size_t)row * 1024);
#pragma unroll
  for (int j = 0; j < 4; ++j) {
    const int f = j * 64 + lane;
    float4 xr = xr4[f];
    float4 gv = ((const float4*)g)[f];
    float4 bv = ((const float4*)bb)[f];
    float4 o;
    o.x = xr.x + (v[j].x - mu) * rstd * gv.x + bv.x;
    o.y = xr.y + (v[j].y - mu) * rstd * gv.y + bv.y;
    o.z = xr.z + (v[j].z - mu) * rstd * gv.z + bv.z;
    o.w = xr.w + (v[j].w - mu) * rstd * gv.w + bv.w;
    of4[f] = o;
  }
}

// ---------------------------------------------------------------------------
extern "C" void kernel_launch(void* const* d_in, const int* in_sizes, int n_in,
                              void* d_out, int out_size, void* d_ws, size_t ws_size,
                              hipStream_t stream) {
  const float* x     = (const float*)d_in[0];
  const float* w_qkv = (const float*)d_in[1];
  const float* ln1_g = (const float*)d_in[2];
  const float* ln1_b = (const float*)d_in[3];
  const float* w1    = (const float*)d_in[4];
  const float* b1    = (const float*)d_in[5];
  const float* w2    = (const float*)d_in[6];
  const float* b2    = (const float*)d_in[7];
  const float* ln2_g = (const float*)d_in[8];
  const float* ln2_b = (const float*)d_in[9];
  float* out = (float*)d_out;
  char* ws = (char*)d_ws;

  // workspace (lifetime-aliased; max end = 98,566,144 B):
  u16*   xb    = (u16*)(ws + 0);              // [0,8.4M)     dead after qkv gemm
  u16*   wqkvT = (u16*)(ws + 8388608);        // [8.4,14.7M)  dead after qkv gemm
  u16*   qkvb  = (u16*)(ws + 31457280);       // [31.5,56.6M) dead after attn
  u16*   vT    = (u16*)(ws + 56623104);       // [56.6,73.4M) dead after attn
  float* Op0   = (float*)(ws + 0);            // [0,16.8M)    attn partial 0 (over dead xb/wqkvT)
  float* Op1   = (float*)(ws + 73400320);     // [73.4,90.2M) attn partial 1
  float* lp    = (float*)(ws + 90177536);     // [90.2,90.7M) l partials (2x256KB)
  float* x1    = (float*)(ws + 31457280);     // [31.5,48.2M) over dead qkvb (after attn)
  u16*   x1b   = (u16*)(ws + 48234496);       // [48.2,56.6M) over dead qkvb; dead after FFN1
  u16*   w1T   = (u16*)(ws + 14680064);       // [14.7,23.1M) written after LN1 (over dead Op0)
  u16*   w2T   = (u16*)(ws + 23068672);       // [23.1,31.5M) written after LN1
  u16*   h1    = (u16*)(ws + 56623104);       // [56.6,90.2M) over dead vT+Op1
  u16*   fp0   = (u16*)(ws + 0);              // FFN2 partials (over dead Op0/lp/x1b)
  u16*   fp1   = (u16*)(ws + 8388608);
  u16*   fp2   = (u16*)(ws + 48234496);
  u16*   fp3   = (u16*)(ws + 90177536);

  // prep1: x->bf16 convert + wqkv transpose (fused, 4096+3072 blocks)
  prep1_kernel<<<7168, 256, 0, stream>>>(x, xb, w_qkv, wqkvT);

  // qkv: M=4096 N=3072 K=1024 -> 256x192 tiles, 16x16 = 256 blocks (full fill)
  gemm_qkv_kernel<<<256, 1024, 0, stream>>>(xb, wqkvT, qkvb);
  transpose_v_kernel<<<dim3(32, 32), 256, 0, stream>>>(qkvb, vT);
  attn_kernel<<<dim3(32, 16, 2), 256, 0, stream>>>(qkvb, vT, Op0, Op1, lp);

  ln_attn_kernel<<<1024, 256, 0, stream>>>(
      Op0, Op1, lp, lp + 4096 * 16, x, ln1_g, ln1_b, x1, x1b);

  // prep2: w1 + w2 transposes (fused, 4096+4096 blocks)
  prep2_kernel<<<8192, 256, 0, stream>>>(w1, w1T, w2, w2T);

  // FFN1: M=4096 N=4096 K=1024 -> 256 blocks
  gemm256_kernel<<<dim3(256, 1), 1024, 0, stream>>>(
      x1b, w1T, b1, h1, 4096, 4096, 1024, 1,
      nullptr, nullptr, nullptr);
  // FFN2: M=4096 N=1024 K=4096, split-K=4 -> 64x4 blocks
  gemm256_kernel<<<dim3(64, 4), 1024, 0, stream>>>(
      h1, w2T, nullptr, fp0, 4096, 1024, 4096, 0,
      fp1, fp2, fp3);

  ln_ffn_kernel<<<1024, 256, 0, stream>>>(
      fp0, fp1, fp2, fp3, b2, x1, ln2_g, ln2_b, out);
}